// Round 8
// baseline (66.338 us; speedup 1.0000x reference)
//
#include <hip/hip_runtime.h>

#define Bn 8
#define Hn 128
#define Wn 128
#define Cn 64
#define Dn 16
#define NS 26                 // 5*5 neighbors + self
#define NPX (Bn * Hn * Wn)    // 131072 pixels

// padded k geometry: per (plane,b) a 132x132 uint4 image (2-px zero border)
#define KPW 132
#define KP_IMG (KPW * KPW)    // 17424 uint4

// ws layout: [0,16KB) packed f16 weights | wsQ uint4[8][NPX] | kpad uint4[8][8][KP_IMG]
#define WS_Q_OFF_B   16384
#define WS_KP_OFF_B  (WS_Q_OFF_B + 8 * NPX * 16)
#define WS_NEEDED    ((size_t)WS_KP_OFF_B + (size_t)64 * KP_IMG * 16)

typedef _Float16 h2 __attribute__((ext_vector_type(2)));

__device__ __forceinline__ unsigned int pkf16(float a, float b) {
    return __builtin_bit_cast(unsigned int, __builtin_amdgcn_cvt_pkrtz(a, b));
}
__device__ __forceinline__ float dot2(unsigned int a, unsigned int b, float c) {
    return __builtin_amdgcn_fdot2(__builtin_bit_cast(h2, a),
                                  __builtin_bit_cast(h2, b), c, false);
}

// ---- prep: pack W (blocks 0-15) + zero kpad borders (blocks 16-275) ----
__global__ void prep(const float* __restrict__ Wm,
                     const float* __restrict__ Wr,
                     unsigned int* __restrict__ wp,
                     uint4* __restrict__ kp) {
    const int blk = blockIdx.x;
    if (blk < 16) {
        const int idx = blk * 256 + threadIdx.x;     // [0,4096)
        const int t = idx >> 11;
        const int r = idx & 2047;
        const int h = r >> 9;
        const int m = (r >> 4) & 31;
        const int d = r & 15;
        const float* W = t ? Wr : Wm;
        wp[idx] = pkf16(W[h * (Cn * Dn) + (2 * m) * Dn + d],
                        W[h * (Cn * Dn) + (2 * m + 1) * Dn + d]);
    } else {
        const int t = (blk - 16) * 256 + threadIdx.x;  // [0, 64*1040)
        const int pb = t / 1040;                       // (plane,b) pair
        const int r  = t - pb * 1040;
        int row, col;
        if (r < 528) {                 // rows {0,1,130,131} full width
            const int q = r / 132;
            row = (q < 2) ? q : 128 + q;
            col = r - q * 132;
        } else {                       // rows 2..129, cols {0,1,130,131}
            const int r2 = r - 528;
            const int s = r2 & 3;
            row = 2 + (r2 >> 2);
            col = (s < 2) ? s : 128 + s;
        }
        kp[pb * KP_IMG + row * KPW + col] = make_uint4(0, 0, 0, 0);
    }
}

__device__ __forceinline__ void proj16(const float4* sIn, int lane,
                                       const unsigned int* wh, float* acc) {
#pragma unroll
    for (int c4 = 0; c4 < 16; ++c4) {
        const float4 v = sIn[lane * 17 + c4];
        const unsigned int a01 = pkf16(v.x, v.y);
        const unsigned int a23 = pkf16(v.z, v.w);
        const unsigned int* w0 = wh + (2 * c4) * Dn;
        const unsigned int* w1 = wh + (2 * c4 + 1) * Dn;
#pragma unroll
        for (int d = 0; d < Dn; ++d) acc[d] = dot2(a01, w0[d], acc[d]);
#pragma unroll
        for (int d = 0; d < Dn; ++d) acc[d] = dot2(a23, w1[d], acc[d]);
    }
}

// ---- pass 1: q,k once per px-head; q planar, k into padded images.
// T14 split: ref tile global loads issued BEFORE the q-compute. ----
__global__ __launch_bounds__(256, 3)
void proj_qk(const float* __restrict__ mainp,
             const float* __restrict__ refp,
             const unsigned int* __restrict__ wp,
             uint4* __restrict__ wsQ,
             uint4* __restrict__ kp)
{
    __shared__ float4 sIn[64 * 17];   // 17408 B

    const int tid  = threadIdx.x;
    const int lane = tid & 63;
    const int wv   = tid >> 6;
    const int head = __builtin_amdgcn_readfirstlane(wv);
    const int pxbase = blockIdx.x * 64;

    const unsigned int* wmh = wp + head * (32 * Dn);
    const unsigned int* wrh = wp + 2048 + head * (32 * Dn);

    // stage main tile (64 px x 64 ch), coalesced
    const float4* mp4 = (const float4*)mainp + (size_t)pxbase * 16;
#pragma unroll
    for (int t = 0; t < 4; ++t) {
        const int idx = t * 256 + tid;
        sIn[(idx >> 4) * 17 + (idx & 15)] = mp4[idx];
    }
    __syncthreads();

    // issue ref tile loads NOW; latency hides under the q-compute
    const float4* rp4 = (const float4*)refp + (size_t)pxbase * 16;
    float4 rreg[4];
#pragma unroll
    for (int t = 0; t < 4; ++t) rreg[t] = rp4[t * 256 + tid];

    float acc[Dn];
#pragma unroll
    for (int d = 0; d < Dn; ++d) acc[d] = 0.f;
    proj16(sIn, lane, wmh, acc);
    wsQ[(head * 2 + 0) * NPX + pxbase + lane] =
        make_uint4(pkf16(acc[0], acc[1]),  pkf16(acc[2], acc[3]),
                   pkf16(acc[4], acc[5]),  pkf16(acc[6], acc[7]));
    wsQ[(head * 2 + 1) * NPX + pxbase + lane] =
        make_uint4(pkf16(acc[8], acc[9]),  pkf16(acc[10], acc[11]),
                   pkf16(acc[12], acc[13]), pkf16(acc[14], acc[15]));

    __syncthreads();   // all reads of main tile done
#pragma unroll
    for (int t = 0; t < 4; ++t) {
        const int idx = t * 256 + tid;
        sIn[(idx >> 4) * 17 + (idx & 15)] = rreg[t];
    }
    __syncthreads();

#pragma unroll
    for (int d = 0; d < Dn; ++d) acc[d] = 0.f;
    proj16(sIn, lane, wrh, acc);
    {
        const int px  = pxbase + lane;
        const int bb  = px >> 14;          // / (128*128)
        const int rem = px & 16383;
        const int yy  = rem >> 7;
        const int xx  = rem & 127;
        const int o   = (yy + 2) * KPW + (xx + 2);
        kp[((head * 2 + 0) * 8 + bb) * KP_IMG + o] =
            make_uint4(pkf16(acc[0], acc[1]),  pkf16(acc[2], acc[3]),
                       pkf16(acc[4], acc[5]),  pkf16(acc[6], acc[7]));
        kp[((head * 2 + 1) * 8 + bb) * KP_IMG + o] =
            make_uint4(pkf16(acc[8], acc[9]),  pkf16(acc[10], acc[11]),
                       pkf16(acc[12], acc[13]), pkf16(acc[14], acc[15]));
    }
}

// ---- pass 2: wave = head x 64-px row segment. k loads are full-wave
// contiguous shifted runs from the padded images: no masks, no k LDS,
// no barriers before softmax. LDS = 13.3 KB combine buffer only. ----
__global__ __launch_bounds__(256, 4)
void attn_row(const uint4* __restrict__ wsQ,
              const uint4* __restrict__ kp,
              float* __restrict__ out)
{
    __shared__ unsigned int sP[4 * 64 * 13];   // 13312 B

    const int tid  = threadIdx.x;
    const int lane = tid & 63;
    const int wv   = tid >> 6;
    const int head = __builtin_amdgcn_readfirstlane(wv);
    const int x0   = blockIdx.x * 64;
    const int y    = blockIdx.y;
    const int b    = blockIdx.z;
    const int pxf  = (b * Hn + y) * Wn + x0 + lane;

    const uint4 qa = wsQ[(head * 2 + 0) * NPX + pxf];
    const uint4 qb = wsQ[(head * 2 + 1) * NPX + pxf];

    const uint4* klo = kp + ((head * 2 + 0) * 8 + b) * KP_IMG;
    const uint4* khi = kp + ((head * 2 + 1) * 8 + b) * KP_IMG;

    float sc[NS];
#pragma unroll
    for (int di = 0; di < 5; ++di) {
        const int p0 = (y + di) * KPW + x0 + lane;   // padded row y+di-2, col x-2
        uint4 kl[5], kh[5];
#pragma unroll
        for (int dj = 0; dj < 5; ++dj) { kl[dj] = klo[p0 + dj]; kh[dj] = khi[p0 + dj]; }
#pragma unroll
        for (int dj = 0; dj < 5; ++dj) {
            float s0 = dot2(qa.x, kl[dj].x, 0.f);
            float s1 = dot2(qb.x, kh[dj].x, 0.f);
            s0 = dot2(qa.y, kl[dj].y, s0);
            s1 = dot2(qb.y, kh[dj].y, s1);
            s0 = dot2(qa.z, kl[dj].z, s0);
            s1 = dot2(qb.z, kh[dj].z, s1);
            s0 = dot2(qa.w, kl[dj].w, s0);
            s1 = dot2(qb.w, kh[dj].w, s1);
            sc[di * 5 + dj] = s0 + s1;
        }
    }
    {   // self score q.q
        float s0 = dot2(qa.x, qa.x, 0.f);
        float s1 = dot2(qb.x, qb.x, 0.f);
        s0 = dot2(qa.y, qa.y, s0);
        s1 = dot2(qb.y, qb.y, s1);
        s0 = dot2(qa.z, qa.z, s0);
        s1 = dot2(qb.z, qb.z, s1);
        s0 = dot2(qa.w, qa.w, s0);
        s1 = dot2(qb.w, qb.w, s1);
        sc[25] = s0 + s1;
    }

    // softmax
    float mx = sc[0];
#pragma unroll
    for (int i = 1; i < NS; ++i) mx = fmaxf(mx, sc[i]);
    float ssum = 0.f;
#pragma unroll
    for (int i = 0; i < NS; ++i) { sc[i] = __expf(sc[i] - mx); ssum += sc[i]; }
    const float inv = 1.0f / ssum;
#pragma unroll
    for (int i = 0; i < NS; ++i) sc[i] *= inv;

    // u16 fixed-point attn -> LDS [head][px][13 pair-words]
    {
        unsigned int* myrow = sP + (wv * 64 + lane) * 13;
#pragma unroll
        for (int j = 0; j < 13; ++j) {
            const unsigned int ulo = (unsigned int)(sc[2 * j] * 65535.f + 0.5f);
            const unsigned int uhi = (unsigned int)(sc[2 * j + 1] * 65535.f + 0.5f);
            myrow[j] = ulo | (uhi << 16);
        }
    }
    __syncthreads();

    // head-mean + store: 64 px x 26 floats = 1664 contiguous floats
    const size_t ob = ((size_t)(b * Hn + y) * Wn + x0) * NS;
    for (int idx = tid; idx < 64 * 13; idx += 256) {
        const int px = idx / 13;
        const int p  = idx - px * 13;
        const unsigned int u0 = sP[(0 * 64 + px) * 13 + p];
        const unsigned int u1 = sP[(1 * 64 + px) * 13 + p];
        const unsigned int u2 = sP[(2 * 64 + px) * 13 + p];
        const unsigned int u3 = sP[(3 * 64 + px) * 13 + p];
        const float lo = (float)((u0 & 0xffffu) + (u1 & 0xffffu) +
                                 (u2 & 0xffffu) + (u3 & 0xffffu));
        const float hi = (float)((u0 >> 16) + (u1 >> 16) + (u2 >> 16) + (u3 >> 16));
        const float k = 1.f / (4.f * 65535.f);
        *(float2*)(out + ob + (size_t)px * NS + 2 * p) = make_float2(lo * k, hi * k);
    }
}

// ================= fallback: R4 monolithic (needs only 16 KB ws) ==========
#define TILE 8
#define HALO 12
#define NHALO (HALO * HALO)
#define PXW 36
__global__ __launch_bounds__(256, 4)
void local_attn_fused_r4(const float* __restrict__ mainp,
                         const float* __restrict__ refp,
                         const unsigned int* __restrict__ wp,
                         float* __restrict__ out)
{
    __shared__ unsigned int sK[NHALO * PXW];
    const int tid  = threadIdx.x;
    const int lane = tid & 63;
    const int wv   = tid >> 6;
    const int head = __builtin_amdgcn_readfirstlane(wv);
    const int b    = blockIdx.z;
    const int y0   = blockIdx.y * TILE;
    const int x0   = blockIdx.x * TILE;
    const unsigned int* wmh = wp + head * (32 * Dn);
    const unsigned int* wrh = wp + 2048 + head * (32 * Dn);
    for (int p = lane; p < NHALO; p += 64) {
        const int hr = p / HALO;
        const int hc = p - hr * HALO;
        const int gy = y0 - 2 + hr;
        const int gx = x0 - 2 + hc;
        float acc[Dn];
#pragma unroll
        for (int d = 0; d < Dn; ++d) acc[d] = 0.f;
        if ((unsigned)gy < (unsigned)Hn && (unsigned)gx < (unsigned)Wn) {
            const float4* rp4 = (const float4*)(refp + (((size_t)b * Hn + gy) * Wn + gx) * Cn);
#pragma unroll
            for (int c4 = 0; c4 < Cn / 4; ++c4) {
                const float4 rv = rp4[c4];
                const unsigned int r01 = pkf16(rv.x, rv.y);
                const unsigned int r23 = pkf16(rv.z, rv.w);
                const unsigned int* w0 = wrh + (2 * c4) * Dn;
                const unsigned int* w1 = wrh + (2 * c4 + 1) * Dn;
#pragma unroll
                for (int d = 0; d < Dn; ++d) acc[d] = dot2(r01, w0[d], acc[d]);
#pragma unroll
                for (int d = 0; d < Dn; ++d) acc[d] = dot2(r23, w1[d], acc[d]);
            }
        }
        unsigned int pk[8];
#pragma unroll
        for (int j = 0; j < 8; ++j) pk[j] = pkf16(acc[2 * j], acc[2 * j + 1]);
        unsigned int* dst = sK + p * PXW + head * 8;
        *(uint4*)(dst)     = make_uint4(pk[0], pk[1], pk[2], pk[3]);
        *(uint4*)(dst + 4) = make_uint4(pk[4], pk[5], pk[6], pk[7]);
    }
    const int pr = lane >> 3;
    const int pc = lane & 7;
    const float4* mp4 = (const float4*)(mainp + (((size_t)b * Hn + (y0 + pr)) * Wn + (x0 + pc)) * Cn);
    float q[Dn];
#pragma unroll
    for (int d = 0; d < Dn; ++d) q[d] = 0.f;
#pragma unroll
    for (int c4 = 0; c4 < Cn / 4; ++c4) {
        const float4 mv = mp4[c4];
        const unsigned int m01 = pkf16(mv.x, mv.y);
        const unsigned int m23 = pkf16(mv.z, mv.w);
        const unsigned int* w0 = wmh + (2 * c4) * Dn;
        const unsigned int* w1 = wmh + (2 * c4 + 1) * Dn;
#pragma unroll
        for (int d = 0; d < Dn; ++d) q[d] = dot2(m01, w0[d], q[d]);
#pragma unroll
        for (int d = 0; d < Dn; ++d) q[d] = dot2(m23, w1[d], q[d]);
    }
    unsigned int qh[8];
#pragma unroll
    for (int j = 0; j < 8; ++j) qh[j] = pkf16(q[2 * j], q[2 * j + 1]);
    __syncthreads();
    float sc[NS];
#pragma unroll
    for (int di = 0; di < 5; ++di) {
#pragma unroll
        for (int dj = 0; dj < 5; ++dj) {
            const int h = (pr + di) * HALO + (pc + dj);
            const unsigned int* src = sK + h * PXW + head * 8;
            const uint4 ka = *(const uint4*)(src);
            const uint4 kb = *(const uint4*)(src + 4);
            float s;
            s = dot2(qh[0], ka.x, 0.f);
            s = dot2(qh[1], ka.y, s);
            s = dot2(qh[2], ka.z, s);
            s = dot2(qh[3], ka.w, s);
            s = dot2(qh[4], kb.x, s);
            s = dot2(qh[5], kb.y, s);
            s = dot2(qh[6], kb.z, s);
            s = dot2(qh[7], kb.w, s);
            sc[di * 5 + dj] = s;
        }
    }
    {
        float s = q[0] * q[0];
#pragma unroll
        for (int d = 1; d < Dn; ++d) s = fmaf(q[d], q[d], s);
        sc[25] = s;
    }
    float mx = sc[0];
#pragma unroll
    for (int i = 1; i < NS; ++i) mx = fmaxf(mx, sc[i]);
    float ssum = 0.f;
#pragma unroll
    for (int i = 0; i < NS; ++i) { sc[i] = __expf(sc[i] - mx); ssum += sc[i]; }
    const float inv = 1.0f / ssum;
#pragma unroll
    for (int i = 0; i < NS; ++i) sc[i] *= inv;
    __syncthreads();
    {
        unsigned int* myrow = sK + (wv * 64 + lane) * 14;
#pragma unroll
        for (int j = 0; j < 13; ++j) myrow[j] = pkf16(sc[2 * j], sc[2 * j + 1]);
    }
    __syncthreads();
    const unsigned short* sA = (const unsigned short*)sK;
    const size_t obase = (((size_t)b * Hn + y0) * Wn + x0) * NS;
    for (int idx = tid; idx < TILE * TILE * NS; idx += 256) {
        const int r   = idx / (TILE * NS);
        const int t   = idx - r * (TILE * NS);
        const int c   = t / NS;
        const int i   = t - c * NS;
        const int ppx = r * TILE + c;
        float acc = 0.f;
#pragma unroll
        for (int h = 0; h < 4; ++h)
            acc += (float)__builtin_bit_cast(_Float16, sA[(h * 64 + ppx) * 28 + i]);
        out[obase + (size_t)r * (Wn * NS) + t] = 0.25f * acc;
    }
}

extern "C" void kernel_launch(void* const* d_in, const int* in_sizes, int n_in,
                              void* d_out, int out_size, void* d_ws, size_t ws_size,
                              hipStream_t stream) {
    (void)in_sizes; (void)n_in; (void)out_size;
    const float* mainp = (const float*)d_in[0];
    const float* refp  = (const float*)d_in[1];
    const float* Wm    = (const float*)d_in[2];
    const float* Wr    = (const float*)d_in[3];
    unsigned int* wpk  = (unsigned int*)d_ws;
    float* out = (float*)d_out;

    if (ws_size >= WS_NEEDED) {
        uint4* wsQ = (uint4*)((char*)d_ws + WS_Q_OFF_B);
        uint4* kp  = (uint4*)((char*)d_ws + WS_KP_OFF_B);
        prep<<<276, 256, 0, stream>>>(Wm, Wr, wpk, kp);
        proj_qk<<<NPX / 64, 256, 0, stream>>>(mainp, refp, wpk, wsQ, kp);
        dim3 grid2(Wn / 64, Hn, Bn);                   // 2 x 128 x 8 = 2048
        attn_row<<<grid2, 256, 0, stream>>>(wsQ, kp, out);
    } else {
        prep<<<16, 256, 0, stream>>>(Wm, Wr, wpk, (uint4*)wpk);  // pack only
        dim3 grid2(Wn / TILE, Hn / TILE, Bn);
        local_attn_fused_r4<<<grid2, 256, 0, stream>>>(mainp, refp, wpk, out);
    }
}

// Round 9
// 48.594 us; speedup vs baseline: 1.3651x; 1.3651x over previous
//
#include <hip/hip_runtime.h>

#define Bn 8
#define Hn 128
#define Wn 128
#define Cn 64
#define Dn 16
#define NS 26                 // 5*5 neighbors + self
#define NPX (Bn * Hn * Wn)    // 131072 pixels

// padded k geometry: per (plane,b) a 132x132 uint4 image (2-px zero border)
#define KPW 132
#define KP_IMG (KPW * KPW)    // 17424 uint4

// ws layout: [0,16KB) MFMA B-fragments | wsQ uint4[8][NPX] | kpad uint4[8][8][KP_IMG]
#define WS_Q_OFF_B   16384
#define WS_KP_OFF_B  (WS_Q_OFF_B + 8 * NPX * 16)
#define WS_NEEDED    ((size_t)WS_KP_OFF_B + (size_t)64 * KP_IMG * 16)

typedef _Float16 h2   __attribute__((ext_vector_type(2)));
typedef _Float16 f16x8 __attribute__((ext_vector_type(8)));
typedef float    f32x4 __attribute__((ext_vector_type(4)));

__device__ __forceinline__ unsigned int pkf16(float a, float b) {
    return __builtin_bit_cast(unsigned int, __builtin_amdgcn_cvt_pkrtz(a, b));
}
__device__ __forceinline__ float dot2(unsigned int a, unsigned int b, float c) {
    return __builtin_amdgcn_fdot2(__builtin_bit_cast(h2, a),
                                  __builtin_bit_cast(h2, b), c, false);
}
__device__ __forceinline__ f16x8 pk8(float4 a, float4 b) {
    const uint4 u = make_uint4(pkf16(a.x, a.y), pkf16(a.z, a.w),
                               pkf16(b.x, b.y), pkf16(b.z, b.w));
    return __builtin_bit_cast(f16x8, u);
}

// ---- prep: MFMA B-fragments (blocks 0-3) + zero kpad borders (4-263) ----
// wf[((ty*4 + h)*2 + kt)*64 + lane] : lane holds W[c = kt*32+(lane>>4)*8+j][d=lane&15]
__global__ void prep(const float* __restrict__ Wm,
                     const float* __restrict__ Wr,
                     uint4* __restrict__ wf,
                     uint4* __restrict__ kp) {
    const int blk = blockIdx.x;
    if (blk < 4) {
        const int idx = blk * 256 + threadIdx.x;   // [0,1024)
        const int ty = idx >> 9;
        const int h  = (idx >> 7) & 3;
        const int kt = (idx >> 6) & 1;
        const int l  = idx & 63;
        const int dd = l & 15;
        const int cb = kt * 32 + (l >> 4) * 8;
        const float* W = ty ? Wr : Wm;
        const float* base = W + h * (Cn * Dn) + dd;
        uint4 v;
        v.x = pkf16(base[(cb + 0) * Dn], base[(cb + 1) * Dn]);
        v.y = pkf16(base[(cb + 2) * Dn], base[(cb + 3) * Dn]);
        v.z = pkf16(base[(cb + 4) * Dn], base[(cb + 5) * Dn]);
        v.w = pkf16(base[(cb + 6) * Dn], base[(cb + 7) * Dn]);
        wf[idx] = v;
    } else {
        const int t = (blk - 4) * 256 + threadIdx.x;  // [0, 64*1040)
        const int pb = t / 1040;                      // (plane,b) pair
        const int r  = t - pb * 1040;
        int row, col;
        if (r < 528) {                 // rows {0,1,130,131} full width
            const int q = r / 132;
            row = (q < 2) ? q : 128 + q;
            col = r - q * 132;
        } else {                       // rows 2..129, cols {0,1,130,131}
            const int r2 = r - 528;
            const int s = r2 & 3;
            row = 2 + (r2 >> 2);
            col = (s < 2) ? s : 128 + s;
        }
        kp[pb * KP_IMG + row * KPW + col] = make_uint4(0, 0, 0, 0);
    }
}

// ---- pass 1: MFMA projection. Wave = 16 px x all 4 heads, q and k.
// Weights live in VGPR B-fragments (no scalar-load streaming).  C-frag
// (col=lane&15,row=(lane>>4)*4+r, m89-verified) -> LDS transpose -> planar
// q / padded k, both f16-packed. ----
__global__ __launch_bounds__(256, 4)
void proj_mfma(const float* __restrict__ mainp,
               const float* __restrict__ refp,
               const uint4* __restrict__ wf,
               uint4* __restrict__ wsQ,
               uint4* __restrict__ kp)
{
    __shared__ _Float16 sT[4][16][72];   // per-wave 16px x 64dim, 72-stride

    const int tid  = threadIdx.x;
    const int lane = tid & 63;
    const int wv   = tid >> 6;
    const int gbase = blockIdx.x * 64 + wv * 16;
    const int row = lane & 15;
    const int lg  = lane >> 4;

    // B fragments: 16 coalesced uint4 loads, held in VGPRs
    f16x8 bm[4][2], br[4][2];
#pragma unroll
    for (int h = 0; h < 4; ++h)
#pragma unroll
        for (int t = 0; t < 2; ++t) {
            bm[h][t] = __builtin_bit_cast(f16x8, wf[(h * 2 + t) * 64 + lane]);
            br[h][t] = __builtin_bit_cast(f16x8, wf[((4 + h) * 2 + t) * 64 + lane]);
        }

    // A fragments: lane = (row px, k-group), 8 consecutive channels
    const float* mrow = mainp + (size_t)(gbase + row) * Cn + lg * 8;
    const float* rrow = refp  + (size_t)(gbase + row) * Cn + lg * 8;
    const float4 m0 = *(const float4*)(mrow);
    const float4 m1 = *(const float4*)(mrow + 4);
    const float4 m2 = *(const float4*)(mrow + 32);
    const float4 m3 = *(const float4*)(mrow + 36);
    const float4 r0 = *(const float4*)(rrow);
    const float4 r1 = *(const float4*)(rrow + 4);
    const float4 r2 = *(const float4*)(rrow + 32);
    const float4 r3 = *(const float4*)(rrow + 36);
    const f16x8 Am0 = pk8(m0, m1), Am1 = pk8(m2, m3);
    const f16x8 Ar0 = pk8(r0, r1), Ar1 = pk8(r2, r3);

    f32x4 qacc[4], kacc[4];
#pragma unroll
    for (int h = 0; h < 4; ++h) {
        f32x4 z = {0.f, 0.f, 0.f, 0.f};
        z = __builtin_amdgcn_mfma_f32_16x16x32_f16(Am0, bm[h][0], z, 0, 0, 0);
        qacc[h] = __builtin_amdgcn_mfma_f32_16x16x32_f16(Am1, bm[h][1], z, 0, 0, 0);
        f32x4 z2 = {0.f, 0.f, 0.f, 0.f};
        z2 = __builtin_amdgcn_mfma_f32_16x16x32_f16(Ar0, br[h][0], z2, 0, 0, 0);
        kacc[h] = __builtin_amdgcn_mfma_f32_16x16x32_f16(Ar1, br[h][1], z2, 0, 0, 0);
    }

    _Float16* T = &sT[wv][0][0];
    // ---- q: transpose via LDS, store planar [w=head*2+half][px] ----
#pragma unroll
    for (int h = 0; h < 4; ++h)
#pragma unroll
        for (int r = 0; r < 4; ++r)
            T[(lg * 4 + r) * 72 + h * 16 + row] = (_Float16)qacc[h][r];
    __syncthreads();
#pragma unroll
    for (int g2 = 0; g2 < 2; ++g2) {
        const int w = lg + g2 * 4;
        const uint4 v = *(const uint4*)&T[row * 72 + w * 8];
        wsQ[(size_t)w * NPX + gbase + row] = v;
    }
    __syncthreads();
    // ---- k: transpose, store padded image ----
#pragma unroll
    for (int h = 0; h < 4; ++h)
#pragma unroll
        for (int r = 0; r < 4; ++r)
            T[(lg * 4 + r) * 72 + h * 16 + row] = (_Float16)kacc[h][r];
    __syncthreads();
    {
        const int px = gbase + row;
        const int bb = px >> 14;
        const int yy = (px & 16383) >> 7;
        const int xx = px & 127;
        const int o  = (yy + 2) * KPW + (xx + 2);
#pragma unroll
        for (int g2 = 0; g2 < 2; ++g2) {
            const int w = lg + g2 * 4;
            const uint4 v = *(const uint4*)&T[row * 72 + w * 8];
            kp[(size_t)(w * 8 + bb) * KP_IMG + o] = v;
        }
    }
}

// ---- pass 2: wave = head x 64-px row segment; contiguous shifted k runs
// from the padded images; no masks, no k LDS, no pre-softmax barriers. ----
__global__ __launch_bounds__(256, 4)
void attn_row(const uint4* __restrict__ wsQ,
              const uint4* __restrict__ kp,
              float* __restrict__ out)
{
    __shared__ unsigned int sP[4 * 64 * 13];   // 13312 B

    const int tid  = threadIdx.x;
    const int lane = tid & 63;
    const int wv   = tid >> 6;
    const int head = __builtin_amdgcn_readfirstlane(wv);
    const int x0   = blockIdx.x * 64;
    const int y    = blockIdx.y;
    const int b    = blockIdx.z;
    const int pxf  = (b * Hn + y) * Wn + x0 + lane;

    const uint4 qa = wsQ[(head * 2 + 0) * NPX + pxf];
    const uint4 qb = wsQ[(head * 2 + 1) * NPX + pxf];

    const uint4* klo = kp + ((head * 2 + 0) * 8 + b) * KP_IMG;
    const uint4* khi = kp + ((head * 2 + 1) * 8 + b) * KP_IMG;

    float sc[NS];
#pragma unroll
    for (int di = 0; di < 5; ++di) {
        const int p0 = (y + di) * KPW + x0 + lane;   // padded row y+di-2, col x-2
        uint4 kl[5], kh[5];
#pragma unroll
        for (int dj = 0; dj < 5; ++dj) { kl[dj] = klo[p0 + dj]; kh[dj] = khi[p0 + dj]; }
#pragma unroll
        for (int dj = 0; dj < 5; ++dj) {
            float s0 = dot2(qa.x, kl[dj].x, 0.f);
            float s1 = dot2(qb.x, kh[dj].x, 0.f);
            s0 = dot2(qa.y, kl[dj].y, s0);
            s1 = dot2(qb.y, kh[dj].y, s1);
            s0 = dot2(qa.z, kl[dj].z, s0);
            s1 = dot2(qb.z, kh[dj].z, s1);
            s0 = dot2(qa.w, kl[dj].w, s0);
            s1 = dot2(qb.w, kh[dj].w, s1);
            sc[di * 5 + dj] = s0 + s1;
        }
    }
    {   // self score q.q
        float s0 = dot2(qa.x, qa.x, 0.f);
        float s1 = dot2(qb.x, qb.x, 0.f);
        s0 = dot2(qa.y, qa.y, s0);
        s1 = dot2(qb.y, qb.y, s1);
        s0 = dot2(qa.z, qa.z, s0);
        s1 = dot2(qb.z, qb.z, s1);
        s0 = dot2(qa.w, qa.w, s0);
        s1 = dot2(qb.w, qb.w, s1);
        sc[25] = s0 + s1;
    }

    // softmax
    float mx = sc[0];
#pragma unroll
    for (int i = 1; i < NS; ++i) mx = fmaxf(mx, sc[i]);
    float ssum = 0.f;
#pragma unroll
    for (int i = 0; i < NS; ++i) { sc[i] = __expf(sc[i] - mx); ssum += sc[i]; }
    const float inv = 1.0f / ssum;
#pragma unroll
    for (int i = 0; i < NS; ++i) sc[i] *= inv;

    // u16 fixed-point attn -> LDS [head][px][13 pair-words]
    {
        unsigned int* myrow = sP + (wv * 64 + lane) * 13;
#pragma unroll
        for (int j = 0; j < 13; ++j) {
            const unsigned int ulo = (unsigned int)(sc[2 * j] * 65535.f + 0.5f);
            const unsigned int uhi = (unsigned int)(sc[2 * j + 1] * 65535.f + 0.5f);
            myrow[j] = ulo | (uhi << 16);
        }
    }
    __syncthreads();

    // head-mean + store: 64 px x 26 floats = 1664 contiguous floats
    const size_t ob = ((size_t)(b * Hn + y) * Wn + x0) * NS;
    for (int idx = tid; idx < 64 * 13; idx += 256) {
        const int px = idx / 13;
        const int p  = idx - px * 13;
        const unsigned int u0 = sP[(0 * 64 + px) * 13 + p];
        const unsigned int u1 = sP[(1 * 64 + px) * 13 + p];
        const unsigned int u2 = sP[(2 * 64 + px) * 13 + p];
        const unsigned int u3 = sP[(3 * 64 + px) * 13 + p];
        const float lo = (float)((u0 & 0xffffu) + (u1 & 0xffffu) +
                                 (u2 & 0xffffu) + (u3 & 0xffffu));
        const float hi = (float)((u0 >> 16) + (u1 >> 16) + (u2 >> 16) + (u3 >> 16));
        const float k = 1.f / (4.f * 65535.f);
        *(float2*)(out + ob + (size_t)px * NS + 2 * p) = make_float2(lo * k, hi * k);
    }
}

// ================= fallback path (small ws): R4 monolithic ==========
#define TILE 8
#define HALO 12
#define NHALO (HALO * HALO)
#define PXW 36
__global__ void pack_weights(const float* __restrict__ Wm,
                             const float* __restrict__ Wr,
                             unsigned int* __restrict__ wp) {
    const int idx = blockIdx.x * 256 + threadIdx.x;
    if (idx < 2 * 4 * 32 * Dn) {
        const int t = idx >> 11;
        const int r = idx & 2047;
        const int h = r >> 9;
        const int m = (r >> 4) & 31;
        const int d = r & 15;
        const float* W = t ? Wr : Wm;
        wp[idx] = pkf16(W[h * (Cn * Dn) + (2 * m) * Dn + d],
                        W[h * (Cn * Dn) + (2 * m + 1) * Dn + d]);
    }
}
__global__ __launch_bounds__(256, 4)
void local_attn_fused_r4(const float* __restrict__ mainp,
                         const float* __restrict__ refp,
                         const unsigned int* __restrict__ wp,
                         float* __restrict__ out)
{
    __shared__ unsigned int sK[NHALO * PXW];
    const int tid  = threadIdx.x;
    const int lane = tid & 63;
    const int wv   = tid >> 6;
    const int head = __builtin_amdgcn_readfirstlane(wv);
    const int b    = blockIdx.z;
    const int y0   = blockIdx.y * TILE;
    const int x0   = blockIdx.x * TILE;
    const unsigned int* wmh = wp + head * (32 * Dn);
    const unsigned int* wrh = wp + 2048 + head * (32 * Dn);
    for (int p = lane; p < NHALO; p += 64) {
        const int hr = p / HALO;
        const int hc = p - hr * HALO;
        const int gy = y0 - 2 + hr;
        const int gx = x0 - 2 + hc;
        float acc[Dn];
#pragma unroll
        for (int d = 0; d < Dn; ++d) acc[d] = 0.f;
        if ((unsigned)gy < (unsigned)Hn && (unsigned)gx < (unsigned)Wn) {
            const float4* rp4 = (const float4*)(refp + (((size_t)b * Hn + gy) * Wn + gx) * Cn);
#pragma unroll
            for (int c4 = 0; c4 < Cn / 4; ++c4) {
                const float4 rv = rp4[c4];
                const unsigned int r01 = pkf16(rv.x, rv.y);
                const unsigned int r23 = pkf16(rv.z, rv.w);
                const unsigned int* w0 = wrh + (2 * c4) * Dn;
                const unsigned int* w1 = wrh + (2 * c4 + 1) * Dn;
#pragma unroll
                for (int d = 0; d < Dn; ++d) acc[d] = dot2(r01, w0[d], acc[d]);
#pragma unroll
                for (int d = 0; d < Dn; ++d) acc[d] = dot2(r23, w1[d], acc[d]);
            }
        }
        unsigned int pk[8];
#pragma unroll
        for (int j = 0; j < 8; ++j) pk[j] = pkf16(acc[2 * j], acc[2 * j + 1]);
        unsigned int* dst = sK + p * PXW + head * 8;
        *(uint4*)(dst)     = make_uint4(pk[0], pk[1], pk[2], pk[3]);
        *(uint4*)(dst + 4) = make_uint4(pk[4], pk[5], pk[6], pk[7]);
    }
    const int pr = lane >> 3;
    const int pc = lane & 7;
    const float4* mp4 = (const float4*)(mainp + (((size_t)b * Hn + (y0 + pr)) * Wn + (x0 + pc)) * Cn);
    float q[Dn];
#pragma unroll
    for (int d = 0; d < Dn; ++d) q[d] = 0.f;
#pragma unroll
    for (int c4 = 0; c4 < Cn / 4; ++c4) {
        const float4 mv = mp4[c4];
        const unsigned int m01 = pkf16(mv.x, mv.y);
        const unsigned int m23 = pkf16(mv.z, mv.w);
        const unsigned int* w0 = wmh + (2 * c4) * Dn;
        const unsigned int* w1 = wmh + (2 * c4 + 1) * Dn;
#pragma unroll
        for (int d = 0; d < Dn; ++d) q[d] = dot2(m01, w0[d], q[d]);
#pragma unroll
        for (int d = 0; d < Dn; ++d) q[d] = dot2(m23, w1[d], q[d]);
    }
    unsigned int qh[8];
#pragma unroll
    for (int j = 0; j < 8; ++j) qh[j] = pkf16(q[2 * j], q[2 * j + 1]);
    __syncthreads();
    float sc[NS];
#pragma unroll
    for (int di = 0; di < 5; ++di) {
#pragma unroll
        for (int dj = 0; dj < 5; ++dj) {
            const int h = (pr + di) * HALO + (pc + dj);
            const unsigned int* src = sK + h * PXW + head * 8;
            const uint4 ka = *(const uint4*)(src);
            const uint4 kb = *(const uint4*)(src + 4);
            float s;
            s = dot2(qh[0], ka.x, 0.f);
            s = dot2(qh[1], ka.y, s);
            s = dot2(qh[2], ka.z, s);
            s = dot2(qh[3], ka.w, s);
            s = dot2(qh[4], kb.x, s);
            s = dot2(qh[5], kb.y, s);
            s = dot2(qh[6], kb.z, s);
            s = dot2(qh[7], kb.w, s);
            sc[di * 5 + dj] = s;
        }
    }
    {
        float s = q[0] * q[0];
#pragma unroll
        for (int d = 1; d < Dn; ++d) s = fmaf(q[d], q[d], s);
        sc[25] = s;
    }
    float mx = sc[0];
#pragma unroll
    for (int i = 1; i < NS; ++i) mx = fmaxf(mx, sc[i]);
    float ssum = 0.f;
#pragma unroll
    for (int i = 0; i < NS; ++i) { sc[i] = __expf(sc[i] - mx); ssum += sc[i]; }
    const float inv = 1.0f / ssum;
#pragma unroll
    for (int i = 0; i < NS; ++i) sc[i] *= inv;
    __syncthreads();
    {
        unsigned int* myrow = sK + (wv * 64 + lane) * 14;
#pragma unroll
        for (int j = 0; j < 13; ++j) myrow[j] = pkf16(sc[2 * j], sc[2 * j + 1]);
    }
    __syncthreads();
    const unsigned short* sA = (const unsigned short*)sK;
    const size_t obase = (((size_t)b * Hn + y0) * Wn + x0) * NS;
    for (int idx = tid; idx < TILE * TILE * NS; idx += 256) {
        const int r   = idx / (TILE * NS);
        const int t   = idx - r * (TILE * NS);
        const int c   = t / NS;
        const int i   = t - c * NS;
        const int ppx = r * TILE + c;
        float acc = 0.f;
#pragma unroll
        for (int h = 0; h < 4; ++h)
            acc += (float)__builtin_bit_cast(_Float16, sA[(h * 64 + ppx) * 28 + i]);
        out[obase + (size_t)r * (Wn * NS) + t] = 0.25f * acc;
    }
}

extern "C" void kernel_launch(void* const* d_in, const int* in_sizes, int n_in,
                              void* d_out, int out_size, void* d_ws, size_t ws_size,
                              hipStream_t stream) {
    (void)in_sizes; (void)n_in; (void)out_size;
    const float* mainp = (const float*)d_in[0];
    const float* refp  = (const float*)d_in[1];
    const float* Wm    = (const float*)d_in[2];
    const float* Wr    = (const float*)d_in[3];
    float* out = (float*)d_out;

    if (ws_size >= WS_NEEDED) {
        uint4* wf  = (uint4*)d_ws;
        uint4* wsQ = (uint4*)((char*)d_ws + WS_Q_OFF_B);
        uint4* kp  = (uint4*)((char*)d_ws + WS_KP_OFF_B);
        prep<<<264, 256, 0, stream>>>(Wm, Wr, wf, kp);
        proj_mfma<<<NPX / 64, 256, 0, stream>>>(mainp, refp, wf, wsQ, kp);
        dim3 grid2(Wn / 64, Hn, Bn);                   // 2 x 128 x 8 = 2048
        attn_row<<<grid2, 256, 0, stream>>>(wsQ, kp, out);
    } else {
        unsigned int* wpk = (unsigned int*)d_ws;
        pack_weights<<<16, 256, 0, stream>>>(Wm, Wr, wpk);
        dim3 grid2(Wn / TILE, Hn / TILE, Bn);
        local_attn_fused_r4<<<grid2, 256, 0, stream>>>(mainp, refp, wpk, out);
    }
}

// Round 10
// 44.740 us; speedup vs baseline: 1.4827x; 1.0861x over previous
//
#include <hip/hip_runtime.h>

#define Bn 8
#define Hn 128
#define Wn 128
#define Cn 64
#define Dn 16
#define NS 26                 // 5*5 neighbors + self
#define NPX (Bn * Hn * Wn)    // 131072 pixels

// padded k geometry: per (plane,b) a 132x132 uint4 image (2-px zero border)
#define KPW 132
#define KP_IMG (KPW * KPW)    // 17424 uint4

// ws layout: [0,16KB) MFMA W-fragments | wsQ uint4[8][NPX] | kpad uint4[8][8][KP_IMG]
#define WS_Q_OFF_B   16384
#define WS_KP_OFF_B  (WS_Q_OFF_B + 8 * NPX * 16)
#define WS_NEEDED    ((size_t)WS_KP_OFF_B + (size_t)64 * KP_IMG * 16)

typedef _Float16 h2    __attribute__((ext_vector_type(2)));
typedef _Float16 f16x8 __attribute__((ext_vector_type(8)));
typedef float    f32x4 __attribute__((ext_vector_type(4)));

__device__ __forceinline__ unsigned int pkf16(float a, float b) {
    return __builtin_bit_cast(unsigned int, __builtin_amdgcn_cvt_pkrtz(a, b));
}
__device__ __forceinline__ float dot2(unsigned int a, unsigned int b, float c) {
    return __builtin_amdgcn_fdot2(__builtin_bit_cast(h2, a),
                                  __builtin_bit_cast(h2, b), c, false);
}
__device__ __forceinline__ f16x8 pk8(float4 a, float4 b) {
    const uint4 u = make_uint4(pkf16(a.x, a.y), pkf16(a.z, a.w),
                               pkf16(b.x, b.y), pkf16(b.z, b.w));
    return __builtin_bit_cast(f16x8, u);
}

// ---- prep: MFMA W-fragments (blocks 0-3) + zero kpad borders (4-263) ----
// wf[((ty*4 + h)*2 + kt)*64 + lane] : lane holds W[c = kt*32+(lane>>4)*8+j][d=lane&15]
__global__ void prep(const float* __restrict__ Wm,
                     const float* __restrict__ Wr,
                     uint4* __restrict__ wf,
                     uint4* __restrict__ kp) {
    const int blk = blockIdx.x;
    if (blk < 4) {
        const int idx = blk * 256 + threadIdx.x;   // [0,1024)
        const int ty = idx >> 9;
        const int h  = (idx >> 7) & 3;
        const int kt = (idx >> 6) & 1;
        const int l  = idx & 63;
        const int dd = l & 15;
        const int cb = kt * 32 + (l >> 4) * 8;
        const float* W = ty ? Wr : Wm;
        const float* base = W + h * (Cn * Dn) + dd;
        uint4 v;
        v.x = pkf16(base[(cb + 0) * Dn], base[(cb + 1) * Dn]);
        v.y = pkf16(base[(cb + 2) * Dn], base[(cb + 3) * Dn]);
        v.z = pkf16(base[(cb + 4) * Dn], base[(cb + 5) * Dn]);
        v.w = pkf16(base[(cb + 6) * Dn], base[(cb + 7) * Dn]);
        wf[idx] = v;
    } else {
        const int t = (blk - 4) * 256 + threadIdx.x;  // [0, 64*1040)
        const int pb = t / 1040;                      // (plane,b) pair
        const int r  = t - pb * 1040;
        int row, col;
        if (r < 528) {                 // rows {0,1,130,131} full width
            const int q = r / 132;
            row = (q < 2) ? q : 128 + q;
            col = r - q * 132;
        } else {                       // rows 2..129, cols {0,1,130,131}
            const int r2 = r - 528;
            const int s = r2 & 3;
            row = 2 + (r2 >> 2);
            col = (s < 2) ? s : 128 + s;
        }
        kp[pb * KP_IMG + row * KPW + col] = make_uint4(0, 0, 0, 0);
    }
}

// ---- pass 1: MFMA projection with SWAPPED operands: D[d][px].
// col=px=lane&15 -> each lane owns d-pairs of one pixel -> direct packed
// uint2 global stores. No LDS, no barriers. ----
__global__ __launch_bounds__(256, 3)
void proj_mfma(const float* __restrict__ mainp,
               const float* __restrict__ refp,
               const uint4* __restrict__ wf,
               uint2* __restrict__ wsQ2,
               uint2* __restrict__ kp2)
{
    const int tid  = threadIdx.x;
    const int lane = tid & 63;
    const int wv   = tid >> 6;
    const int gbase = blockIdx.x * 64 + wv * 16;
    const int px16 = lane & 15;
    const int lg   = lane >> 4;

    // input fragments first (HBM latency); 8 consecutive channels per lane
    const float* mrow = mainp + (size_t)(gbase + px16) * Cn + lg * 8;
    const float* rrow = refp  + (size_t)(gbase + px16) * Cn + lg * 8;
    const float4 m0 = *(const float4*)(mrow);
    const float4 m1 = *(const float4*)(mrow + 4);
    const float4 m2 = *(const float4*)(mrow + 32);
    const float4 m3 = *(const float4*)(mrow + 36);
    const float4 r0 = *(const float4*)(rrow);
    const float4 r1 = *(const float4*)(rrow + 4);
    const float4 r2 = *(const float4*)(rrow + 32);
    const float4 r3 = *(const float4*)(rrow + 36);

    // weight fragments (L2-resident, 16 KB shared by all blocks)
    f16x8 bm[4][2], br[4][2];
#pragma unroll
    for (int h = 0; h < 4; ++h)
#pragma unroll
        for (int t = 0; t < 2; ++t) {
            bm[h][t] = __builtin_bit_cast(f16x8, wf[(h * 2 + t) * 64 + lane]);
            br[h][t] = __builtin_bit_cast(f16x8, wf[((4 + h) * 2 + t) * 64 + lane]);
        }

    const f16x8 Am0 = pk8(m0, m1), Am1 = pk8(m2, m3);
    const f16x8 Ar0 = pk8(r0, r1), Ar1 = pk8(r2, r3);

    const int px = gbase + px16;
    const int bb = px >> 14;
    const int yy = (px & 16383) >> 7;
    const int xx = px & 127;
    const int o  = (yy + 2) * KPW + (xx + 2);
    const int halfsel  = lg >> 1;   // which 8-d half plane
    const int wordpair = lg & 1;    // uint2 slot within the 16B record

    // q: D[d][px] = W_main^T . main^T  (A=W frag, B=x frag)
#pragma unroll
    for (int h = 0; h < 4; ++h) {
        f32x4 z = {0.f, 0.f, 0.f, 0.f};
        z = __builtin_amdgcn_mfma_f32_16x16x32_f16(bm[h][0], Am0, z, 0, 0, 0);
        z = __builtin_amdgcn_mfma_f32_16x16x32_f16(bm[h][1], Am1, z, 0, 0, 0);
        const int w = h * 2 + halfsel;
        wsQ2[(size_t)w * NPX * 2 + px * 2 + wordpair] =
            make_uint2(pkf16(z[0], z[1]), pkf16(z[2], z[3]));
    }
    // k: same for ref, into the padded images
#pragma unroll
    for (int h = 0; h < 4; ++h) {
        f32x4 z = {0.f, 0.f, 0.f, 0.f};
        z = __builtin_amdgcn_mfma_f32_16x16x32_f16(br[h][0], Ar0, z, 0, 0, 0);
        z = __builtin_amdgcn_mfma_f32_16x16x32_f16(br[h][1], Ar1, z, 0, 0, 0);
        const int w = h * 2 + halfsel;
        kp2[((size_t)(w * 8 + bb) * KP_IMG + o) * 2 + wordpair] =
            make_uint2(pkf16(z[0], z[1]), pkf16(z[2], z[3]));
    }
}

// ---- pass 2: wave = head x 64-px row segment; contiguous shifted k runs
// from the padded images. XCD-chunked swizzle maps batch b -> XCD b so the
// per-XCD k working set (2.2 MB) stays L2-resident. ----
__global__ __launch_bounds__(256, 4)
void attn_row(const uint4* __restrict__ wsQ,
              const uint4* __restrict__ kp,
              float* __restrict__ out)
{
    __shared__ unsigned int sP[4 * 64 * 13];   // 13312 B

    const int tid  = threadIdx.x;
    const int lane = tid & 63;
    const int wv   = tid >> 6;
    const int head = __builtin_amdgcn_readfirstlane(wv);
    // chunked XCD swizzle over 2048 = 8 x 256 blocks
    const int wg = blockIdx.x;
    const int sw = (wg & 7) * 256 + (wg >> 3);
    const int b  = sw >> 8;
    const int y  = (sw >> 1) & 127;
    const int x0 = (sw & 1) * 64;
    const int pxf = (b * Hn + y) * Wn + x0 + lane;

    const uint4 qa = wsQ[(head * 2 + 0) * NPX + pxf];
    const uint4 qb = wsQ[(head * 2 + 1) * NPX + pxf];

    const uint4* klo = kp + ((head * 2 + 0) * 8 + b) * KP_IMG;
    const uint4* khi = kp + ((head * 2 + 1) * 8 + b) * KP_IMG;

    float sc[NS];
#pragma unroll
    for (int di = 0; di < 5; ++di) {
        const int p0 = (y + di) * KPW + x0 + lane;   // padded row y+di-2, col x-2
        uint4 kl[5], kh[5];
#pragma unroll
        for (int dj = 0; dj < 5; ++dj) { kl[dj] = klo[p0 + dj]; kh[dj] = khi[p0 + dj]; }
#pragma unroll
        for (int dj = 0; dj < 5; ++dj) {
            float s0 = dot2(qa.x, kl[dj].x, 0.f);
            float s1 = dot2(qb.x, kh[dj].x, 0.f);
            s0 = dot2(qa.y, kl[dj].y, s0);
            s1 = dot2(qb.y, kh[dj].y, s1);
            s0 = dot2(qa.z, kl[dj].z, s0);
            s1 = dot2(qb.z, kh[dj].z, s1);
            s0 = dot2(qa.w, kl[dj].w, s0);
            s1 = dot2(qb.w, kh[dj].w, s1);
            sc[di * 5 + dj] = s0 + s1;
        }
    }
    {   // self score q.q
        float s0 = dot2(qa.x, qa.x, 0.f);
        float s1 = dot2(qb.x, qb.x, 0.f);
        s0 = dot2(qa.y, qa.y, s0);
        s1 = dot2(qb.y, qb.y, s1);
        s0 = dot2(qa.z, qa.z, s0);
        s1 = dot2(qb.z, qb.z, s1);
        s0 = dot2(qa.w, qa.w, s0);
        s1 = dot2(qb.w, qb.w, s1);
        sc[25] = s0 + s1;
    }

    // softmax
    float mx = sc[0];
#pragma unroll
    for (int i = 1; i < NS; ++i) mx = fmaxf(mx, sc[i]);
    float ssum = 0.f;
#pragma unroll
    for (int i = 0; i < NS; ++i) { sc[i] = __expf(sc[i] - mx); ssum += sc[i]; }
    const float inv = 1.0f / ssum;
#pragma unroll
    for (int i = 0; i < NS; ++i) sc[i] *= inv;

    // u16 fixed-point attn -> LDS [head][px][13 pair-words]
    {
        unsigned int* myrow = sP + (wv * 64 + lane) * 13;
#pragma unroll
        for (int j = 0; j < 13; ++j) {
            const unsigned int ulo = (unsigned int)(sc[2 * j] * 65535.f + 0.5f);
            const unsigned int uhi = (unsigned int)(sc[2 * j + 1] * 65535.f + 0.5f);
            myrow[j] = ulo | (uhi << 16);
        }
    }
    __syncthreads();

    // head-mean + store: 64 px x 26 floats = 1664 contiguous floats
    const size_t ob = ((size_t)(b * Hn + y) * Wn + x0) * NS;
    for (int idx = tid; idx < 64 * 13; idx += 256) {
        const int px = idx / 13;
        const int p  = idx - px * 13;
        const unsigned int u0 = sP[(0 * 64 + px) * 13 + p];
        const unsigned int u1 = sP[(1 * 64 + px) * 13 + p];
        const unsigned int u2 = sP[(2 * 64 + px) * 13 + p];
        const unsigned int u3 = sP[(3 * 64 + px) * 13 + p];
        const float lo = (float)((u0 & 0xffffu) + (u1 & 0xffffu) +
                                 (u2 & 0xffffu) + (u3 & 0xffffu));
        const float hi = (float)((u0 >> 16) + (u1 >> 16) + (u2 >> 16) + (u3 >> 16));
        const float k = 1.f / (4.f * 65535.f);
        *(float2*)(out + ob + (size_t)px * NS + 2 * p) = make_float2(lo * k, hi * k);
    }
}

// ================= fallback path (small ws): R4 monolithic ==========
#define TILE 8
#define HALO 12
#define NHALO (HALO * HALO)
#define PXW 36
__global__ void pack_weights(const float* __restrict__ Wm,
                             const float* __restrict__ Wr,
                             unsigned int* __restrict__ wp) {
    const int idx = blockIdx.x * 256 + threadIdx.x;
    if (idx < 2 * 4 * 32 * Dn) {
        const int t = idx >> 11;
        const int r = idx & 2047;
        const int h = r >> 9;
        const int m = (r >> 4) & 31;
        const int d = r & 15;
        const float* W = t ? Wr : Wm;
        wp[idx] = pkf16(W[h * (Cn * Dn) + (2 * m) * Dn + d],
                        W[h * (Cn * Dn) + (2 * m + 1) * Dn + d]);
    }
}
__global__ __launch_bounds__(256, 4)
void local_attn_fused_r4(const float* __restrict__ mainp,
                         const float* __restrict__ refp,
                         const unsigned int* __restrict__ wp,
                         float* __restrict__ out)
{
    __shared__ unsigned int sK[NHALO * PXW];
    const int tid  = threadIdx.x;
    const int lane = tid & 63;
    const int wv   = tid >> 6;
    const int head = __builtin_amdgcn_readfirstlane(wv);
    const int b    = blockIdx.z;
    const int y0   = blockIdx.y * TILE;
    const int x0   = blockIdx.x * TILE;
    const unsigned int* wmh = wp + head * (32 * Dn);
    const unsigned int* wrh = wp + 2048 + head * (32 * Dn);
    for (int p = lane; p < NHALO; p += 64) {
        const int hr = p / HALO;
        const int hc = p - hr * HALO;
        const int gy = y0 - 2 + hr;
        const int gx = x0 - 2 + hc;
        float acc[Dn];
#pragma unroll
        for (int d = 0; d < Dn; ++d) acc[d] = 0.f;
        if ((unsigned)gy < (unsigned)Hn && (unsigned)gx < (unsigned)Wn) {
            const float4* rp4 = (const float4*)(refp + (((size_t)b * Hn + gy) * Wn + gx) * Cn);
#pragma unroll
            for (int c4 = 0; c4 < Cn / 4; ++c4) {
                const float4 rv = rp4[c4];
                const unsigned int r01 = pkf16(rv.x, rv.y);
                const unsigned int r23 = pkf16(rv.z, rv.w);
                const unsigned int* w0 = wrh + (2 * c4) * Dn;
                const unsigned int* w1 = wrh + (2 * c4 + 1) * Dn;
#pragma unroll
                for (int d = 0; d < Dn; ++d) acc[d] = dot2(r01, w0[d], acc[d]);
#pragma unroll
                for (int d = 0; d < Dn; ++d) acc[d] = dot2(r23, w1[d], acc[d]);
            }
        }
        unsigned int pk[8];
#pragma unroll
        for (int j = 0; j < 8; ++j) pk[j] = pkf16(acc[2 * j], acc[2 * j + 1]);
        unsigned int* dst = sK + p * PXW + head * 8;
        *(uint4*)(dst)     = make_uint4(pk[0], pk[1], pk[2], pk[3]);
        *(uint4*)(dst + 4) = make_uint4(pk[4], pk[5], pk[6], pk[7]);
    }
    const int pr = lane >> 3;
    const int pc = lane & 7;
    const float4* mp4 = (const float4*)(mainp + (((size_t)b * Hn + (y0 + pr)) * Wn + (x0 + pc)) * Cn);
    float q[Dn];
#pragma unroll
    for (int d = 0; d < Dn; ++d) q[d] = 0.f;
#pragma unroll
    for (int c4 = 0; c4 < Cn / 4; ++c4) {
        const float4 mv = mp4[c4];
        const unsigned int m01 = pkf16(mv.x, mv.y);
        const unsigned int m23 = pkf16(mv.z, mv.w);
        const unsigned int* w0 = wmh + (2 * c4) * Dn;
        const unsigned int* w1 = wmh + (2 * c4 + 1) * Dn;
#pragma unroll
        for (int d = 0; d < Dn; ++d) q[d] = dot2(m01, w0[d], q[d]);
#pragma unroll
        for (int d = 0; d < Dn; ++d) q[d] = dot2(m23, w1[d], q[d]);
    }
    unsigned int qh[8];
#pragma unroll
    for (int j = 0; j < 8; ++j) qh[j] = pkf16(q[2 * j], q[2 * j + 1]);
    __syncthreads();
    float sc[NS];
#pragma unroll
    for (int di = 0; di < 5; ++di) {
#pragma unroll
        for (int dj = 0; dj < 5; ++dj) {
            const int h = (pr + di) * HALO + (pc + dj);
            const unsigned int* src = sK + h * PXW + head * 8;
            const uint4 ka = *(const uint4*)(src);
            const uint4 kb = *(const uint4*)(src + 4);
            float s;
            s = dot2(qh[0], ka.x, 0.f);
            s = dot2(qh[1], ka.y, s);
            s = dot2(qh[2], ka.z, s);
            s = dot2(qh[3], ka.w, s);
            s = dot2(qh[4], kb.x, s);
            s = dot2(qh[5], kb.y, s);
            s = dot2(qh[6], kb.z, s);
            s = dot2(qh[7], kb.w, s);
            sc[di * 5 + dj] = s;
        }
    }
    {
        float s = q[0] * q[0];
#pragma unroll
        for (int d = 1; d < Dn; ++d) s = fmaf(q[d], q[d], s);
        sc[25] = s;
    }
    float mx = sc[0];
#pragma unroll
    for (int i = 1; i < NS; ++i) mx = fmaxf(mx, sc[i]);
    float ssum = 0.f;
#pragma unroll
    for (int i = 0; i < NS; ++i) { sc[i] = __expf(sc[i] - mx); ssum += sc[i]; }
    const float inv = 1.0f / ssum;
#pragma unroll
    for (int i = 0; i < NS; ++i) sc[i] *= inv;
    __syncthreads();
    {
        unsigned int* myrow = sK + (wv * 64 + lane) * 14;
#pragma unroll
        for (int j = 0; j < 13; ++j) myrow[j] = pkf16(sc[2 * j], sc[2 * j + 1]);
    }
    __syncthreads();
    const unsigned short* sA = (const unsigned short*)sK;
    const size_t obase = (((size_t)b * Hn + y0) * Wn + x0) * NS;
    for (int idx = tid; idx < TILE * TILE * NS; idx += 256) {
        const int r   = idx / (TILE * NS);
        const int t   = idx - r * (TILE * NS);
        const int c   = t / NS;
        const int i   = t - c * NS;
        const int ppx = r * TILE + c;
        float acc = 0.f;
#pragma unroll
        for (int h = 0; h < 4; ++h)
            acc += (float)__builtin_bit_cast(_Float16, sA[(h * 64 + ppx) * 28 + i]);
        out[obase + (size_t)r * (Wn * NS) + t] = 0.25f * acc;
    }
}

extern "C" void kernel_launch(void* const* d_in, const int* in_sizes, int n_in,
                              void* d_out, int out_size, void* d_ws, size_t ws_size,
                              hipStream_t stream) {
    (void)in_sizes; (void)n_in; (void)out_size;
    const float* mainp = (const float*)d_in[0];
    const float* refp  = (const float*)d_in[1];
    const float* Wm    = (const float*)d_in[2];
    const float* Wr    = (const float*)d_in[3];
    float* out = (float*)d_out;

    if (ws_size >= WS_NEEDED) {
        uint4* wf   = (uint4*)d_ws;
        uint4* wsQ  = (uint4*)((char*)d_ws + WS_Q_OFF_B);
        uint4* kp   = (uint4*)((char*)d_ws + WS_KP_OFF_B);
        uint2* wsQ2 = (uint2*)wsQ;
        uint2* kp2  = (uint2*)kp;
        prep<<<264, 256, 0, stream>>>(Wm, Wr, wf, kp);
        proj_mfma<<<NPX / 64, 256, 0, stream>>>(mainp, refp, wf, wsQ2, kp2);
        attn_row<<<2048, 256, 0, stream>>>(wsQ, kp, out);   // 1-D, XCD-swizzled
    } else {
        unsigned int* wpk = (unsigned int*)d_ws;
        pack_weights<<<16, 256, 0, stream>>>(Wm, Wr, wpk);
        dim3 grid2(Wn / TILE, Hn / TILE, Bn);
        local_attn_fused_r4<<<grid2, 256, 0, stream>>>(mainp, refp, wpk, out);
    }
}

// Round 11
// 40.332 us; speedup vs baseline: 1.6448x; 1.1093x over previous
//
#include <hip/hip_runtime.h>

#define Bn 8
#define Hn 128
#define Wn 128
#define Cn 64
#define Dn 16
#define NS 26                 // 5*5 neighbors + self
#define NPX (Bn * Hn * Wn)    // 131072 pixels

// padded k geometry: per (plane,b) a 132x132 uint4 image (2-px zero border)
#define KPW 132
#define KP_IMG (KPW * KPW)    // 17424 uint4
#define NBORD 66560           // 64 images x 1040 border cells

// ws layout: [0,16KB) spare | wsQ uint4[8][NPX] | kpad uint4[8][8][KP_IMG]
#define WS_Q_OFF_B   16384
#define WS_KP_OFF_B  (WS_Q_OFF_B + 8 * NPX * 16)
#define WS_NEEDED    ((size_t)WS_KP_OFF_B + (size_t)64 * KP_IMG * 16)

typedef _Float16 h2    __attribute__((ext_vector_type(2)));
typedef _Float16 f16x8 __attribute__((ext_vector_type(8)));
typedef float    f32x4 __attribute__((ext_vector_type(4)));

__device__ __forceinline__ unsigned int pkf16(float a, float b) {
    return __builtin_bit_cast(unsigned int, __builtin_amdgcn_cvt_pkrtz(a, b));
}
__device__ __forceinline__ float dot2(unsigned int a, unsigned int b, float c) {
    return __builtin_amdgcn_fdot2(__builtin_bit_cast(h2, a),
                                  __builtin_bit_cast(h2, b), c, false);
}
__device__ __forceinline__ f16x8 pk8(float4 a, float4 b) {
    const uint4 u = make_uint4(pkf16(a.x, a.y), pkf16(a.z, a.w),
                               pkf16(b.x, b.y), pkf16(b.z, b.w));
    return __builtin_bit_cast(f16x8, u);
}

// ---- fused pass 1: border-zero + LDS weight pack + MFMA projection ----
// Swapped-operand MFMA: D[d][px], col=px=lane&15 -> direct packed uint2
// stores (R10-verified). Batch->XCD chunked swizzle matches attn_row so k
// is produced and consumed on the same XCD's L2.
__global__ __launch_bounds__(256, 3)
void proj_fused(const float* __restrict__ mainp,
                const float* __restrict__ refp,
                const float* __restrict__ Wm,
                const float* __restrict__ Wr,
                uint2* __restrict__ wsQ2,
                uint2* __restrict__ kp2,
                uint4* __restrict__ kp4)
{
    __shared__ uint4 sW[1024];   // 16 KB fragment-ordered f16 weights

    const int tid = threadIdx.x;
    const int wg  = blockIdx.x;
    const int sw  = ((wg & 7) << 8) | (wg >> 3);   // bijective; batch -> XCD

    // ---- distributed border zeroing (read only by the later attn kernel) ----
    {
        const int idx = wg * 33 + tid;
        if (tid < 33 && idx < NBORD) {
            const int pb = idx / 1040;
            const int r  = idx - pb * 1040;
            int row, col;
            if (r < 528) { const int q = r / 132; row = (q < 2) ? q : 128 + q; col = r - q * 132; }
            else { const int r2 = r - 528; const int s = r2 & 3; row = 2 + (r2 >> 2); col = (s < 2) ? s : 128 + s; }
            kp4[(size_t)pb * KP_IMG + row * KPW + col] = make_uint4(0, 0, 0, 0);
        }
    }

    // ---- cooperative weight pack into LDS (old wf layout) ----
    // entry e = ty*512 + h*128 + kt*64 + l ; lane l holds W[c=kt*32+(l>>4)*8+j][d=l&15]
    for (int e = tid; e < 1024; e += 256) {
        const int ty = e >> 9;
        const int h  = (e >> 7) & 3;
        const int kt = (e >> 6) & 1;
        const int l  = e & 63;
        const int dd = l & 15;
        const int cb = kt * 32 + ((l >> 4) << 3);
        const float* W = ty ? Wr : Wm;
        const float* base = W + h * (Cn * Dn) + dd;
        uint4 v;
        v.x = pkf16(base[(cb + 0) * Dn], base[(cb + 1) * Dn]);
        v.y = pkf16(base[(cb + 2) * Dn], base[(cb + 3) * Dn]);
        v.z = pkf16(base[(cb + 4) * Dn], base[(cb + 5) * Dn]);
        v.w = pkf16(base[(cb + 6) * Dn], base[(cb + 7) * Dn]);
        sW[e] = v;
    }

    // ---- input fragment loads (pre-barrier: HBM latency overlaps pack) ----
    const int lane = tid & 63;
    const int wv   = tid >> 6;
    const int gbase = sw * 64 + wv * 16;
    const int px16 = lane & 15;
    const int lg   = lane >> 4;

    const float* mrow = mainp + (size_t)(gbase + px16) * Cn + lg * 8;
    const float* rrow = refp  + (size_t)(gbase + px16) * Cn + lg * 8;
    const float4 m0 = *(const float4*)(mrow);
    const float4 m1 = *(const float4*)(mrow + 4);
    const float4 m2 = *(const float4*)(mrow + 32);
    const float4 m3 = *(const float4*)(mrow + 36);
    const float4 r0 = *(const float4*)(rrow);
    const float4 r1 = *(const float4*)(rrow + 4);
    const float4 r2 = *(const float4*)(rrow + 32);
    const float4 r3 = *(const float4*)(rrow + 36);

    __syncthreads();

    // weight fragments from LDS (b128, conflict-free: lane-linear)
    f16x8 bm[4][2], br[4][2];
#pragma unroll
    for (int h = 0; h < 4; ++h)
#pragma unroll
        for (int t = 0; t < 2; ++t) {
            bm[h][t] = __builtin_bit_cast(f16x8, sW[(h * 2 + t) * 64 + lane]);
            br[h][t] = __builtin_bit_cast(f16x8, sW[(8 + h * 2 + t) * 64 + lane]);
        }

    const f16x8 Am0 = pk8(m0, m1), Am1 = pk8(m2, m3);
    const f16x8 Ar0 = pk8(r0, r1), Ar1 = pk8(r2, r3);

    const int px = gbase + px16;
    const int bb = px >> 14;
    const int yy = (px & 16383) >> 7;
    const int xx = px & 127;
    const int o  = (yy + 2) * KPW + (xx + 2);
    const int halfsel  = lg >> 1;   // which 8-d half plane
    const int wordpair = lg & 1;    // uint2 slot within the 16B record

    // q: D[d][px] = W_main^T . main^T  (A=W frag, B=x frag)
#pragma unroll
    for (int h = 0; h < 4; ++h) {
        f32x4 z = {0.f, 0.f, 0.f, 0.f};
        z = __builtin_amdgcn_mfma_f32_16x16x32_f16(bm[h][0], Am0, z, 0, 0, 0);
        z = __builtin_amdgcn_mfma_f32_16x16x32_f16(bm[h][1], Am1, z, 0, 0, 0);
        const int w = h * 2 + halfsel;
        wsQ2[(size_t)w * NPX * 2 + px * 2 + wordpair] =
            make_uint2(pkf16(z[0], z[1]), pkf16(z[2], z[3]));
    }
    // k: same for ref, into the padded images
#pragma unroll
    for (int h = 0; h < 4; ++h) {
        f32x4 z = {0.f, 0.f, 0.f, 0.f};
        z = __builtin_amdgcn_mfma_f32_16x16x32_f16(br[h][0], Ar0, z, 0, 0, 0);
        z = __builtin_amdgcn_mfma_f32_16x16x32_f16(br[h][1], Ar1, z, 0, 0, 0);
        const int w = h * 2 + halfsel;
        kp2[((size_t)(w * 8 + bb) * KP_IMG + o) * 2 + wordpair] =
            make_uint2(pkf16(z[0], z[1]), pkf16(z[2], z[3]));
    }
}

// ---- pass 2: wave = head x 64-px row segment; contiguous shifted k runs
// from the padded images. Same batch->XCD swizzle: k is L2-resident. ----
__global__ __launch_bounds__(256, 4)
void attn_row(const uint4* __restrict__ wsQ,
              const uint4* __restrict__ kp,
              float* __restrict__ out)
{
    __shared__ unsigned int sP[4 * 64 * 13];   // 13312 B

    const int tid  = threadIdx.x;
    const int lane = tid & 63;
    const int wv   = tid >> 6;
    const int head = __builtin_amdgcn_readfirstlane(wv);
    const int wg = blockIdx.x;
    const int sw = ((wg & 7) << 8) | (wg >> 3);
    const int b  = sw >> 8;
    const int y  = (sw >> 1) & 127;
    const int x0 = (sw & 1) * 64;
    const int pxf = (b * Hn + y) * Wn + x0 + lane;

    const uint4 qa = wsQ[(head * 2 + 0) * NPX + pxf];
    const uint4 qb = wsQ[(head * 2 + 1) * NPX + pxf];

    const uint4* klo = kp + ((head * 2 + 0) * 8 + b) * KP_IMG;
    const uint4* khi = kp + ((head * 2 + 1) * 8 + b) * KP_IMG;

    float sc[NS];
#pragma unroll
    for (int di = 0; di < 5; ++di) {
        const int p0 = (y + di) * KPW + x0 + lane;   // padded row y+di-2, col x-2
        uint4 kl[5], kh[5];
#pragma unroll
        for (int dj = 0; dj < 5; ++dj) { kl[dj] = klo[p0 + dj]; kh[dj] = khi[p0 + dj]; }
#pragma unroll
        for (int dj = 0; dj < 5; ++dj) {
            float s0 = dot2(qa.x, kl[dj].x, 0.f);
            float s1 = dot2(qb.x, kh[dj].x, 0.f);
            s0 = dot2(qa.y, kl[dj].y, s0);
            s1 = dot2(qb.y, kh[dj].y, s1);
            s0 = dot2(qa.z, kl[dj].z, s0);
            s1 = dot2(qb.z, kh[dj].z, s1);
            s0 = dot2(qa.w, kl[dj].w, s0);
            s1 = dot2(qb.w, kh[dj].w, s1);
            sc[di * 5 + dj] = s0 + s1;
        }
    }
    {   // self score q.q
        float s0 = dot2(qa.x, qa.x, 0.f);
        float s1 = dot2(qb.x, qb.x, 0.f);
        s0 = dot2(qa.y, qa.y, s0);
        s1 = dot2(qb.y, qb.y, s1);
        s0 = dot2(qa.z, qa.z, s0);
        s1 = dot2(qb.z, qb.z, s1);
        s0 = dot2(qa.w, qa.w, s0);
        s1 = dot2(qb.w, qb.w, s1);
        sc[25] = s0 + s1;
    }

    // softmax
    float mx = sc[0];
#pragma unroll
    for (int i = 1; i < NS; ++i) mx = fmaxf(mx, sc[i]);
    float ssum = 0.f;
#pragma unroll
    for (int i = 0; i < NS; ++i) { sc[i] = __expf(sc[i] - mx); ssum += sc[i]; }
    const float inv = 1.0f / ssum;
#pragma unroll
    for (int i = 0; i < NS; ++i) sc[i] *= inv;

    // u16 fixed-point attn -> LDS [head][px][13 pair-words]
    {
        unsigned int* myrow = sP + (wv * 64 + lane) * 13;
#pragma unroll
        for (int j = 0; j < 13; ++j) {
            const unsigned int ulo = (unsigned int)(sc[2 * j] * 65535.f + 0.5f);
            const unsigned int uhi = (unsigned int)(sc[2 * j + 1] * 65535.f + 0.5f);
            myrow[j] = ulo | (uhi << 16);
        }
    }
    __syncthreads();

    // head-mean + store: 64 px x 26 floats = 1664 contiguous floats
    const size_t ob = ((size_t)(b * Hn + y) * Wn + x0) * NS;
    for (int idx = tid; idx < 64 * 13; idx += 256) {
        const int px = idx / 13;
        const int p  = idx - px * 13;
        const unsigned int u0 = sP[(0 * 64 + px) * 13 + p];
        const unsigned int u1 = sP[(1 * 64 + px) * 13 + p];
        const unsigned int u2 = sP[(2 * 64 + px) * 13 + p];
        const unsigned int u3 = sP[(3 * 64 + px) * 13 + p];
        const float lo = (float)((u0 & 0xffffu) + (u1 & 0xffffu) +
                                 (u2 & 0xffffu) + (u3 & 0xffffu));
        const float hi = (float)((u0 >> 16) + (u1 >> 16) + (u2 >> 16) + (u3 >> 16));
        const float k = 1.f / (4.f * 65535.f);
        *(float2*)(out + ob + (size_t)px * NS + 2 * p) = make_float2(lo * k, hi * k);
    }
}

// ================= fallback path (small ws): R4 monolithic ==========
#define TILE 8
#define HALO 12
#define NHALO (HALO * HALO)
#define PXW 36
__global__ void pack_weights(const float* __restrict__ Wm,
                             const float* __restrict__ Wr,
                             unsigned int* __restrict__ wp) {
    const int idx = blockIdx.x * 256 + threadIdx.x;
    if (idx < 2 * 4 * 32 * Dn) {
        const int t = idx >> 11;
        const int r = idx & 2047;
        const int h = r >> 9;
        const int m = (r >> 4) & 31;
        const int d = r & 15;
        const float* W = t ? Wr : Wm;
        wp[idx] = pkf16(W[h * (Cn * Dn) + (2 * m) * Dn + d],
                        W[h * (Cn * Dn) + (2 * m + 1) * Dn + d]);
    }
}
__global__ __launch_bounds__(256, 4)
void local_attn_fused_r4(const float* __restrict__ mainp,
                         const float* __restrict__ refp,
                         const unsigned int* __restrict__ wp,
                         float* __restrict__ out)
{
    __shared__ unsigned int sK[NHALO * PXW];
    const int tid  = threadIdx.x;
    const int lane = tid & 63;
    const int wv   = tid >> 6;
    const int head = __builtin_amdgcn_readfirstlane(wv);
    const int b    = blockIdx.z;
    const int y0   = blockIdx.y * TILE;
    const int x0   = blockIdx.x * TILE;
    const unsigned int* wmh = wp + head * (32 * Dn);
    const unsigned int* wrh = wp + 2048 + head * (32 * Dn);
    for (int p = lane; p < NHALO; p += 64) {
        const int hr = p / HALO;
        const int hc = p - hr * HALO;
        const int gy = y0 - 2 + hr;
        const int gx = x0 - 2 + hc;
        float acc[Dn];
#pragma unroll
        for (int d = 0; d < Dn; ++d) acc[d] = 0.f;
        if ((unsigned)gy < (unsigned)Hn && (unsigned)gx < (unsigned)Wn) {
            const float4* rp4 = (const float4*)(refp + (((size_t)b * Hn + gy) * Wn + gx) * Cn);
#pragma unroll
            for (int c4 = 0; c4 < Cn / 4; ++c4) {
                const float4 rv = rp4[c4];
                const unsigned int r01 = pkf16(rv.x, rv.y);
                const unsigned int r23 = pkf16(rv.z, rv.w);
                const unsigned int* w0 = wrh + (2 * c4) * Dn;
                const unsigned int* w1 = wrh + (2 * c4 + 1) * Dn;
#pragma unroll
                for (int d = 0; d < Dn; ++d) acc[d] = dot2(r01, w0[d], acc[d]);
#pragma unroll
                for (int d = 0; d < Dn; ++d) acc[d] = dot2(r23, w1[d], acc[d]);
            }
        }
        unsigned int pk[8];
#pragma unroll
        for (int j = 0; j < 8; ++j) pk[j] = pkf16(acc[2 * j], acc[2 * j + 1]);
        unsigned int* dst = sK + p * PXW + head * 8;
        *(uint4*)(dst)     = make_uint4(pk[0], pk[1], pk[2], pk[3]);
        *(uint4*)(dst + 4) = make_uint4(pk[4], pk[5], pk[6], pk[7]);
    }
    const int pr = lane >> 3;
    const int pc = lane & 7;
    const float4* mp4 = (const float4*)(mainp + (((size_t)b * Hn + (y0 + pr)) * Wn + (x0 + pc)) * Cn);
    float q[Dn];
#pragma unroll
    for (int d = 0; d < Dn; ++d) q[d] = 0.f;
#pragma unroll
    for (int c4 = 0; c4 < Cn / 4; ++c4) {
        const float4 mv = mp4[c4];
        const unsigned int m01 = pkf16(mv.x, mv.y);
        const unsigned int m23 = pkf16(mv.z, mv.w);
        const unsigned int* w0 = wmh + (2 * c4) * Dn;
        const unsigned int* w1 = wmh + (2 * c4 + 1) * Dn;
#pragma unroll
        for (int d = 0; d < Dn; ++d) q[d] = dot2(m01, w0[d], q[d]);
#pragma unroll
        for (int d = 0; d < Dn; ++d) q[d] = dot2(m23, w1[d], q[d]);
    }
    unsigned int qh[8];
#pragma unroll
    for (int j = 0; j < 8; ++j) qh[j] = pkf16(q[2 * j], q[2 * j + 1]);
    __syncthreads();
    float sc[NS];
#pragma unroll
    for (int di = 0; di < 5; ++di) {
#pragma unroll
        for (int dj = 0; dj < 5; ++dj) {
            const int h = (pr + di) * HALO + (pc + dj);
            const unsigned int* src = sK + h * PXW + head * 8;
            const uint4 ka = *(const uint4*)(src);
            const uint4 kb = *(const uint4*)(src + 4);
            float s;
            s = dot2(qh[0], ka.x, 0.f);
            s = dot2(qh[1], ka.y, s);
            s = dot2(qh[2], ka.z, s);
            s = dot2(qh[3], ka.w, s);
            s = dot2(qh[4], kb.x, s);
            s = dot2(qh[5], kb.y, s);
            s = dot2(qh[6], kb.z, s);
            s = dot2(qh[7], kb.w, s);
            sc[di * 5 + dj] = s;
        }
    }
    {
        float s = q[0] * q[0];
#pragma unroll
        for (int d = 1; d < Dn; ++d) s = fmaf(q[d], q[d], s);
        sc[25] = s;
    }
    float mx = sc[0];
#pragma unroll
    for (int i = 1; i < NS; ++i) mx = fmaxf(mx, sc[i]);
    float ssum = 0.f;
#pragma unroll
    for (int i = 0; i < NS; ++i) { sc[i] = __expf(sc[i] - mx); ssum += sc[i]; }
    const float inv = 1.0f / ssum;
#pragma unroll
    for (int i = 0; i < NS; ++i) sc[i] *= inv;
    __syncthreads();
    {
        unsigned int* myrow = sK + (wv * 64 + lane) * 14;
#pragma unroll
        for (int j = 0; j < 13; ++j) myrow[j] = pkf16(sc[2 * j], sc[2 * j + 1]);
    }
    __syncthreads();
    const unsigned short* sA = (const unsigned short*)sK;
    const size_t obase = (((size_t)b * Hn + y0) * Wn + x0) * NS;
    for (int idx = tid; idx < TILE * TILE * NS; idx += 256) {
        const int r   = idx / (TILE * NS);
        const int t   = idx - r * (TILE * NS);
        const int c   = t / NS;
        const int i   = t - c * NS;
        const int ppx = r * TILE + c;
        float acc = 0.f;
#pragma unroll
        for (int h = 0; h < 4; ++h)
            acc += (float)__builtin_bit_cast(_Float16, sA[(h * 64 + ppx) * 28 + i]);
        out[obase + (size_t)r * (Wn * NS) + t] = 0.25f * acc;
    }
}

extern "C" void kernel_launch(void* const* d_in, const int* in_sizes, int n_in,
                              void* d_out, int out_size, void* d_ws, size_t ws_size,
                              hipStream_t stream) {
    (void)in_sizes; (void)n_in; (void)out_size;
    const float* mainp = (const float*)d_in[0];
    const float* refp  = (const float*)d_in[1];
    const float* Wm    = (const float*)d_in[2];
    const float* Wr    = (const float*)d_in[3];
    float* out = (float*)d_out;

    if (ws_size >= WS_NEEDED) {
        uint4* wsQ  = (uint4*)((char*)d_ws + WS_Q_OFF_B);
        uint4* kp   = (uint4*)((char*)d_ws + WS_KP_OFF_B);
        proj_fused<<<2048, 256, 0, stream>>>(mainp, refp, Wm, Wr,
                                             (uint2*)wsQ, (uint2*)kp, kp);
        attn_row<<<2048, 256, 0, stream>>>(wsQ, kp, out);
    } else {
        unsigned int* wpk = (unsigned int*)d_ws;
        pack_weights<<<16, 256, 0, stream>>>(Wm, Wr, wpk);
        dim3 grid2(Wn / TILE, Hn / TILE, Bn);
        local_attn_fused_r4<<<grid2, 256, 0, stream>>>(mainp, refp, wpk, out);
    }
}

// Round 12
// 36.136 us; speedup vs baseline: 1.8358x; 1.1161x over previous
//
#include <hip/hip_runtime.h>

#define Bn 8
#define Hn 128
#define Wn 128
#define Cn 64
#define Dn 16
#define NS 26                 // 5*5 neighbors + self
#define NPX (Bn * Hn * Wn)    // 131072 pixels

// padded k geometry: per (plane,b) a 132x132 uint4 image (2-px zero border)
#define KPW 132
#define KP_IMG (KPW * KPW)    // 17424 uint4
#define NBORD 66560           // 64 images x 1040 border cells

// ws layout: [0,16KB) spare | [unused q region] | kpad uint4[8][8][KP_IMG]
#define WS_Q_OFF_B   16384
#define WS_KP_OFF_B  (WS_Q_OFF_B + 8 * NPX * 16)
#define WS_NEEDED    ((size_t)WS_KP_OFF_B + (size_t)64 * KP_IMG * 16)

typedef _Float16 h2    __attribute__((ext_vector_type(2)));
typedef _Float16 f16x8 __attribute__((ext_vector_type(8)));
typedef float    f32x4 __attribute__((ext_vector_type(4)));

__device__ __forceinline__ unsigned int pkf16(float a, float b) {
    return __builtin_bit_cast(unsigned int, __builtin_amdgcn_cvt_pkrtz(a, b));
}
__device__ __forceinline__ float dot2(unsigned int a, unsigned int b, float c) {
    return __builtin_amdgcn_fdot2(__builtin_bit_cast(h2, a),
                                  __builtin_bit_cast(h2, b), c, false);
}
__device__ __forceinline__ f16x8 pk8(float4 a, float4 b) {
    const uint4 u = make_uint4(pkf16(a.x, a.y), pkf16(a.z, a.w),
                               pkf16(b.x, b.y), pkf16(b.z, b.w));
    return __builtin_bit_cast(f16x8, u);
}

// ---- pass 1: k-only projection (border-zero + Wr LDS pack + MFMA) ----
// Swapped-operand MFMA: D[d][px], col=px=lane&15 -> direct packed uint2
// stores. Batch->XCD chunked swizzle matches attn so k stays in the
// producing XCD's L2.
__global__ __launch_bounds__(256, 3)
void proj_k(const float* __restrict__ refp,
            const float* __restrict__ Wr,
            uint2* __restrict__ kp2,
            uint4* __restrict__ kp4)
{
    __shared__ uint4 sW[512];   // 8 KB fragment-ordered f16 ref-weights

    const int tid = threadIdx.x;
    const int wg  = blockIdx.x;
    const int sw  = ((wg & 7) << 8) | (wg >> 3);   // bijective; batch -> XCD

    // distributed border zeroing (consumed only by the later attn kernel)
    {
        const int idx = wg * 33 + tid;
        if (tid < 33 && idx < NBORD) {
            const int pb = idx / 1040;
            const int r  = idx - pb * 1040;
            int row, col;
            if (r < 528) { const int q = r / 132; row = (q < 2) ? q : 128 + q; col = r - q * 132; }
            else { const int r2 = r - 528; const int s = r2 & 3; row = 2 + (r2 >> 2); col = (s < 2) ? s : 128 + s; }
            kp4[(size_t)pb * KP_IMG + row * KPW + col] = make_uint4(0, 0, 0, 0);
        }
    }

    // cooperative Wr pack: entry e = h*128 + kt*64 + l
    for (int e = tid; e < 512; e += 256) {
        const int h  = e >> 7;
        const int kt = (e >> 6) & 1;
        const int l  = e & 63;
        const int dd = l & 15;
        const int cb = kt * 32 + ((l >> 4) << 3);
        const float* base = Wr + h * (Cn * Dn) + dd;
        uint4 v;
        v.x = pkf16(base[(cb + 0) * Dn], base[(cb + 1) * Dn]);
        v.y = pkf16(base[(cb + 2) * Dn], base[(cb + 3) * Dn]);
        v.z = pkf16(base[(cb + 4) * Dn], base[(cb + 5) * Dn]);
        v.w = pkf16(base[(cb + 6) * Dn], base[(cb + 7) * Dn]);
        sW[e] = v;
    }

    // ref fragment loads (pre-barrier: HBM latency overlaps the pack)
    const int lane = tid & 63;
    const int wv   = tid >> 6;
    const int gbase = sw * 64 + wv * 16;
    const int px16 = lane & 15;
    const int lg   = lane >> 4;

    const float* rrow = refp + (size_t)(gbase + px16) * Cn + lg * 8;
    const float4 r0 = *(const float4*)(rrow);
    const float4 r1 = *(const float4*)(rrow + 4);
    const float4 r2 = *(const float4*)(rrow + 32);
    const float4 r3 = *(const float4*)(rrow + 36);

    __syncthreads();

    f16x8 br[4][2];
#pragma unroll
    for (int h = 0; h < 4; ++h)
#pragma unroll
        for (int t = 0; t < 2; ++t)
            br[h][t] = __builtin_bit_cast(f16x8, sW[(h * 2 + t) * 64 + lane]);

    const f16x8 Ar0 = pk8(r0, r1), Ar1 = pk8(r2, r3);

    const int px = gbase + px16;
    const int bb = px >> 14;
    const int yy = (px & 16383) >> 7;
    const int xx = px & 127;
    const int o  = (yy + 2) * KPW + (xx + 2);
    const int halfsel  = lg >> 1;
    const int wordpair = lg & 1;

#pragma unroll
    for (int h = 0; h < 4; ++h) {
        f32x4 z = {0.f, 0.f, 0.f, 0.f};
        z = __builtin_amdgcn_mfma_f32_16x16x32_f16(br[h][0], Ar0, z, 0, 0, 0);
        z = __builtin_amdgcn_mfma_f32_16x16x32_f16(br[h][1], Ar1, z, 0, 0, 0);
        const int w = h * 2 + halfsel;
        kp2[((size_t)(w * 8 + bb) * KP_IMG + o) * 2 + wordpair] =
            make_uint2(pkf16(z[0], z[1]), pkf16(z[2], z[3]));
    }
}

// ---- pass 2: fused q-projection + scores. Wave wv builds q for its own
// 16-px group x all heads (MFMA), LDS-exchanges to per-lane full-q, then
// wave = head for the score loop (identical to R11). LDS 21.5 KB:
// region A = Wm-pack (8K) UNION combine buffer (13.3K); region B = sQ 8K.
__global__ __launch_bounds__(256, 3)
void attn_row_fq(const float* __restrict__ mainp,
                 const float* __restrict__ Wm,
                 const uint4* __restrict__ kp,
                 float* __restrict__ out)
{
    __shared__ __align__(16) unsigned int sA_[3328];   // sW(2048w) U sP(3328w)
    __shared__ __align__(16) unsigned int sQ[4 * 64 * 8];   // 8192 B

    const int tid  = threadIdx.x;
    const int lane = tid & 63;
    const int wv   = tid >> 6;
    const int wg = blockIdx.x;
    const int sw = ((wg & 7) << 8) | (wg >> 3);
    const int b  = sw >> 8;
    const int y  = (sw >> 1) & 127;
    const int x0 = (sw & 1) * 64;

    // ---- cooperative Wm pack into region A ----
    uint4* sW = (uint4*)sA_;
    for (int e = tid; e < 512; e += 256) {
        const int h  = e >> 7;
        const int kt = (e >> 6) & 1;
        const int l  = e & 63;
        const int dd = l & 15;
        const int cb = kt * 32 + ((l >> 4) << 3);
        const float* base = Wm + h * (Cn * Dn) + dd;
        uint4 v;
        v.x = pkf16(base[(cb + 0) * Dn], base[(cb + 1) * Dn]);
        v.y = pkf16(base[(cb + 2) * Dn], base[(cb + 3) * Dn]);
        v.z = pkf16(base[(cb + 4) * Dn], base[(cb + 5) * Dn]);
        v.w = pkf16(base[(cb + 6) * Dn], base[(cb + 7) * Dn]);
        sW[e] = v;
    }

    // main B-frag loads for my px-group (pre-barrier)
    const int px16 = lane & 15;
    const int lg   = lane >> 4;
    const float* mrow = mainp +
        (size_t)((b * Hn + y) * Wn + x0 + wv * 16 + px16) * Cn + lg * 8;
    const float4 m0 = *(const float4*)(mrow);
    const float4 m1 = *(const float4*)(mrow + 4);
    const float4 m2 = *(const float4*)(mrow + 32);
    const float4 m3 = *(const float4*)(mrow + 36);

    __syncthreads();   // sW ready

    f16x8 bm[4][2];
#pragma unroll
    for (int h = 0; h < 4; ++h)
#pragma unroll
        for (int t = 0; t < 2; ++t)
            bm[h][t] = __builtin_bit_cast(f16x8, sW[(h * 2 + t) * 64 + lane]);

    const f16x8 Am0 = pk8(m0, m1), Am1 = pk8(m2, m3);
    const int rr = lg;   // output d-row group
#pragma unroll
    for (int h = 0; h < 4; ++h) {
        f32x4 z = {0.f, 0.f, 0.f, 0.f};
        z = __builtin_amdgcn_mfma_f32_16x16x32_f16(bm[h][0], Am0, z, 0, 0, 0);
        z = __builtin_amdgcn_mfma_f32_16x16x32_f16(bm[h][1], Am1, z, 0, 0, 0);
        *(uint2*)&sQ[(h * 64 + wv * 16 + px16) * 8 + rr * 2] =
            make_uint2(pkf16(z[0], z[1]), pkf16(z[2], z[3]));
    }

    __syncthreads();   // sQ ready; sW dead from here on

    const int head = __builtin_amdgcn_readfirstlane(wv);
    const uint4 qa = *(const uint4*)&sQ[(head * 64 + lane) * 8];
    const uint4 qb = *(const uint4*)&sQ[(head * 64 + lane) * 8 + 4];

    const uint4* klo = kp + ((head * 2 + 0) * 8 + b) * KP_IMG;
    const uint4* khi = kp + ((head * 2 + 1) * 8 + b) * KP_IMG;

    float sc[NS];
#pragma unroll
    for (int di = 0; di < 5; ++di) {
        const int p0 = (y + di) * KPW + x0 + lane;   // padded row y+di-2, col x-2
        uint4 kl[5], kh[5];
#pragma unroll
        for (int dj = 0; dj < 5; ++dj) { kl[dj] = klo[p0 + dj]; kh[dj] = khi[p0 + dj]; }
#pragma unroll
        for (int dj = 0; dj < 5; ++dj) {
            float s0 = dot2(qa.x, kl[dj].x, 0.f);
            float s1 = dot2(qb.x, kh[dj].x, 0.f);
            s0 = dot2(qa.y, kl[dj].y, s0);
            s1 = dot2(qb.y, kh[dj].y, s1);
            s0 = dot2(qa.z, kl[dj].z, s0);
            s1 = dot2(qb.z, kh[dj].z, s1);
            s0 = dot2(qa.w, kl[dj].w, s0);
            s1 = dot2(qb.w, kh[dj].w, s1);
            sc[di * 5 + dj] = s0 + s1;
        }
    }
    {   // self score q.q
        float s0 = dot2(qa.x, qa.x, 0.f);
        float s1 = dot2(qb.x, qb.x, 0.f);
        s0 = dot2(qa.y, qa.y, s0);
        s1 = dot2(qb.y, qb.y, s1);
        s0 = dot2(qa.z, qa.z, s0);
        s1 = dot2(qb.z, qb.z, s1);
        s0 = dot2(qa.w, qa.w, s0);
        s1 = dot2(qb.w, qb.w, s1);
        sc[25] = s0 + s1;
    }

    // softmax
    float mx = sc[0];
#pragma unroll
    for (int i = 1; i < NS; ++i) mx = fmaxf(mx, sc[i]);
    float ssum = 0.f;
#pragma unroll
    for (int i = 0; i < NS; ++i) { sc[i] = __expf(sc[i] - mx); ssum += sc[i]; }
    const float inv = 1.0f / ssum;
#pragma unroll
    for (int i = 0; i < NS; ++i) sc[i] *= inv;

    // u16 fixed-point attn -> region A (sW is dead: every wave passed bar 2)
    unsigned int* sP = sA_;
    {
        unsigned int* myrow = sP + (wv * 64 + lane) * 13;
#pragma unroll
        for (int j = 0; j < 13; ++j) {
            const unsigned int ulo = (unsigned int)(sc[2 * j] * 65535.f + 0.5f);
            const unsigned int uhi = (unsigned int)(sc[2 * j + 1] * 65535.f + 0.5f);
            myrow[j] = ulo | (uhi << 16);
        }
    }
    __syncthreads();

    // head-mean + store: 64 px x 26 floats = 1664 contiguous floats
    const size_t ob = ((size_t)(b * Hn + y) * Wn + x0) * NS;
    for (int idx = tid; idx < 64 * 13; idx += 256) {
        const int px = idx / 13;
        const int p  = idx - px * 13;
        const unsigned int u0 = sP[(0 * 64 + px) * 13 + p];
        const unsigned int u1 = sP[(1 * 64 + px) * 13 + p];
        const unsigned int u2 = sP[(2 * 64 + px) * 13 + p];
        const unsigned int u3 = sP[(3 * 64 + px) * 13 + p];
        const float lo = (float)((u0 & 0xffffu) + (u1 & 0xffffu) +
                                 (u2 & 0xffffu) + (u3 & 0xffffu));
        const float hi = (float)((u0 >> 16) + (u1 >> 16) + (u2 >> 16) + (u3 >> 16));
        const float k = 1.f / (4.f * 65535.f);
        *(float2*)(out + ob + (size_t)px * NS + 2 * p) = make_float2(lo * k, hi * k);
    }
}

// ================= fallback path (small ws): R4 monolithic ==========
#define TILE 8
#define HALO 12
#define NHALO (HALO * HALO)
#define PXW 36
__global__ void pack_weights(const float* __restrict__ Wm,
                             const float* __restrict__ Wr,
                             unsigned int* __restrict__ wp) {
    const int idx = blockIdx.x * 256 + threadIdx.x;
    if (idx < 2 * 4 * 32 * Dn) {
        const int t = idx >> 11;
        const int r = idx & 2047;
        const int h = r >> 9;
        const int m = (r >> 4) & 31;
        const int d = r & 15;
        const float* W = t ? Wr : Wm;
        wp[idx] = pkf16(W[h * (Cn * Dn) + (2 * m) * Dn + d],
                        W[h * (Cn * Dn) + (2 * m + 1) * Dn + d]);
    }
}
__global__ __launch_bounds__(256, 4)
void local_attn_fused_r4(const float* __restrict__ mainp,
                         const float* __restrict__ refp,
                         const unsigned int* __restrict__ wp,
                         float* __restrict__ out)
{
    __shared__ unsigned int sK[NHALO * PXW];
    const int tid  = threadIdx.x;
    const int lane = tid & 63;
    const int wv   = tid >> 6;
    const int head = __builtin_amdgcn_readfirstlane(wv);
    const int b    = blockIdx.z;
    const int y0   = blockIdx.y * TILE;
    const int x0   = blockIdx.x * TILE;
    const unsigned int* wmh = wp + head * (32 * Dn);
    const unsigned int* wrh = wp + 2048 + head * (32 * Dn);
    for (int p = lane; p < NHALO; p += 64) {
        const int hr = p / HALO;
        const int hc = p - hr * HALO;
        const int gy = y0 - 2 + hr;
        const int gx = x0 - 2 + hc;
        float acc[Dn];
#pragma unroll
        for (int d = 0; d < Dn; ++d) acc[d] = 0.f;
        if ((unsigned)gy < (unsigned)Hn && (unsigned)gx < (unsigned)Wn) {
            const float4* rp4 = (const float4*)(refp + (((size_t)b * Hn + gy) * Wn + gx) * Cn);
#pragma unroll
            for (int c4 = 0; c4 < Cn / 4; ++c4) {
                const float4 rv = rp4[c4];
                const unsigned int r01 = pkf16(rv.x, rv.y);
                const unsigned int r23 = pkf16(rv.z, rv.w);
                const unsigned int* w0 = wrh + (2 * c4) * Dn;
                const unsigned int* w1 = wrh + (2 * c4 + 1) * Dn;
#pragma unroll
                for (int d = 0; d < Dn; ++d) acc[d] = dot2(r01, w0[d], acc[d]);
#pragma unroll
                for (int d = 0; d < Dn; ++d) acc[d] = dot2(r23, w1[d], acc[d]);
            }
        }
        unsigned int pk[8];
#pragma unroll
        for (int j = 0; j < 8; ++j) pk[j] = pkf16(acc[2 * j], acc[2 * j + 1]);
        unsigned int* dst = sK + p * PXW + head * 8;
        *(uint4*)(dst)     = make_uint4(pk[0], pk[1], pk[2], pk[3]);
        *(uint4*)(dst + 4) = make_uint4(pk[4], pk[5], pk[6], pk[7]);
    }
    const int pr = lane >> 3;
    const int pc = lane & 7;
    const float4* mp4 = (const float4*)(mainp + (((size_t)b * Hn + (y0 + pr)) * Wn + (x0 + pc)) * Cn);
    float q[Dn];
#pragma unroll
    for (int d = 0; d < Dn; ++d) q[d] = 0.f;
#pragma unroll
    for (int c4 = 0; c4 < Cn / 4; ++c4) {
        const float4 mv = mp4[c4];
        const unsigned int m01 = pkf16(mv.x, mv.y);
        const unsigned int m23 = pkf16(mv.z, mv.w);
        const unsigned int* w0 = wmh + (2 * c4) * Dn;
        const unsigned int* w1 = wmh + (2 * c4 + 1) * Dn;
#pragma unroll
        for (int d = 0; d < Dn; ++d) q[d] = dot2(m01, w0[d], q[d]);
#pragma unroll
        for (int d = 0; d < Dn; ++d) q[d] = dot2(m23, w1[d], q[d]);
    }
    unsigned int qh[8];
#pragma unroll
    for (int j = 0; j < 8; ++j) qh[j] = pkf16(q[2 * j], q[2 * j + 1]);
    __syncthreads();
    float sc[NS];
#pragma unroll
    for (int di = 0; di < 5; ++di) {
#pragma unroll
        for (int dj = 0; dj < 5; ++dj) {
            const int h = (pr + di) * HALO + (pc + dj);
            const unsigned int* src = sK + h * PXW + head * 8;
            const uint4 ka = *(const uint4*)(src);
            const uint4 kb = *(const uint4*)(src + 4);
            float s;
            s = dot2(qh[0], ka.x, 0.f);
            s = dot2(qh[1], ka.y, s);
            s = dot2(qh[2], ka.z, s);
            s = dot2(qh[3], ka.w, s);
            s = dot2(qh[4], kb.x, s);
            s = dot2(qh[5], kb.y, s);
            s = dot2(qh[6], kb.z, s);
            s = dot2(qh[7], kb.w, s);
            sc[di * 5 + dj] = s;
        }
    }
    {
        float s = q[0] * q[0];
#pragma unroll
        for (int d = 1; d < Dn; ++d) s = fmaf(q[d], q[d], s);
        sc[25] = s;
    }
    float mx = sc[0];
#pragma unroll
    for (int i = 1; i < NS; ++i) mx = fmaxf(mx, sc[i]);
    float ssum = 0.f;
#pragma unroll
    for (int i = 0; i < NS; ++i) { sc[i] = __expf(sc[i] - mx); ssum += sc[i]; }
    const float inv = 1.0f / ssum;
#pragma unroll
    for (int i = 0; i < NS; ++i) sc[i] *= inv;
    __syncthreads();
    {
        unsigned int* myrow = sK + (wv * 64 + lane) * 14;
#pragma unroll
        for (int j = 0; j < 13; ++j) myrow[j] = pkf16(sc[2 * j], sc[2 * j + 1]);
    }
    __syncthreads();
    const unsigned short* sA = (const unsigned short*)sK;
    const size_t obase = (((size_t)b * Hn + y0) * Wn + x0) * NS;
    for (int idx = tid; idx < TILE * TILE * NS; idx += 256) {
        const int r   = idx / (TILE * NS);
        const int t   = idx - r * (TILE * NS);
        const int c   = t / NS;
        const int i   = t - c * NS;
        const int ppx = r * TILE + c;
        float acc = 0.f;
#pragma unroll
        for (int h = 0; h < 4; ++h)
            acc += (float)__builtin_bit_cast(_Float16, sA[(h * 64 + ppx) * 28 + i]);
        out[obase + (size_t)r * (Wn * NS) + t] = 0.25f * acc;
    }
}

extern "C" void kernel_launch(void* const* d_in, const int* in_sizes, int n_in,
                              void* d_out, int out_size, void* d_ws, size_t ws_size,
                              hipStream_t stream) {
    (void)in_sizes; (void)n_in; (void)out_size;
    const float* mainp = (const float*)d_in[0];
    const float* refp  = (const float*)d_in[1];
    const float* Wm    = (const float*)d_in[2];
    const float* Wr    = (const float*)d_in[3];
    float* out = (float*)d_out;

    if (ws_size >= WS_NEEDED) {
        uint4* kpb = (uint4*)((char*)d_ws + WS_KP_OFF_B);
        proj_k<<<2048, 256, 0, stream>>>(refp, Wr, (uint2*)kpb, kpb);
        attn_row_fq<<<2048, 256, 0, stream>>>(mainp, Wm, kpb, out);
    } else {
        unsigned int* wpk = (unsigned int*)d_ws;
        pack_weights<<<16, 256, 0, stream>>>(Wm, Wr, wpk);
        dim3 grid2(Wn / TILE, Hn / TILE, Bn);
        local_attn_fused_r4<<<grid2, 256, 0, stream>>>(mainp, refp, wpk, out);
    }
}